// Round 1
// baseline (467.033 us; speedup 1.0000x reference)
//
#include <hip/hip_runtime.h>

#define N_NODES 16384
#define F_IN    128
#define F_HID   256
#define F_OUT   128
#define HSIZE   (1u << 20)
#define HMASK   (HSIZE - 1u)
#define EMPTY_KEY 0xFFFFFFFFu
#define LN_EPS  1e-5f

// ---------------------------------------------------------------------------
// Detect whether edge_index arrived as int64 (odd u32 words all zero) or int32.
// Values are uniform in [0,16384): for int32 data the odd words are random edge
// values (P(all 1024 == 0) ~ 0), for int64 they are the always-zero hi words.
__global__ void detect_mode_kernel(const unsigned* ei, int* mode) {
    __shared__ int nz;
    if (threadIdx.x == 0) nz = 0;
    __syncthreads();
    for (int it = 0; it < 4; ++it) {
        int idx = 2 * (threadIdx.x + it * 256) + 1;
        if (ei[idx] != 0u) nz = 1;   // benign race, all writers store 1
    }
    __syncthreads();
    if (threadIdx.x == 0) *mode = (nz == 0) ? 1 : 0;  // 1 => int64
}

// ---------------------------------------------------------------------------
__global__ void init_kernel(unsigned* keys, unsigned* vals, int* cnt, float* deg) {
    int i = blockIdx.x * 256 + threadIdx.x;
    keys[i] = EMPTY_KEY;
    vals[i] = 0u;
    if (i < N_NODES) { cnt[i] = 0; deg[i] = 1.0f; }   // degree starts with self-loop
}

// ---------------------------------------------------------------------------
// Hash insert with last-write-wins: per (r,c) key keep max edge index (e+1).
__global__ void insert_kernel(const void* ei, const int* mode,
                              unsigned* keys, unsigned* vals, int E) {
    int e = blockIdx.x * 256 + threadIdx.x;
    if (e >= E) return;
    int r, c;
    if (*mode) {
        const long long* p = (const long long*)ei;
        r = (int)p[e]; c = (int)p[e + E];
    } else {
        const int* p = (const int*)ei;
        r = p[e]; c = p[e + E];
    }
    unsigned key = ((unsigned)r << 14) | (unsigned)c;
    unsigned slot = (key * 2654435761u) >> 12;   // top 20 bits
    for (;;) {
        unsigned prev = atomicCAS(&keys[slot], EMPTY_KEY, key);
        if (prev == EMPTY_KEY || prev == key) {
            atomicMax(&vals[slot], (unsigned)(e + 1));
            break;
        }
        slot = (slot + 1u) & HMASK;
    }
}

// ---------------------------------------------------------------------------
__global__ void count_kernel(const unsigned* keys, const unsigned* vals, int* cnt) {
    int i = blockIdx.x * 256 + threadIdx.x;
    if (vals[i]) atomicAdd(&cnt[keys[i] >> 14], 1);
}

// ---------------------------------------------------------------------------
// Exclusive scan over 16384 row counts; single block of 256 threads x 64 rows.
// Also zeroes cnt[] so fill_kernel can reuse it as a per-row cursor.
__global__ void scan_kernel(int* cnt, int* rp) {
    __shared__ int part[256];
    int t = threadIdx.x;
    int base = t * 64;
    int s = 0;
    for (int i = 0; i < 64; ++i) s += cnt[base + i];
    part[t] = s;
    __syncthreads();
    for (int off = 1; off < 256; off <<= 1) {
        int v = (t >= off) ? part[t - off] : 0;
        __syncthreads();
        part[t] += v;
        __syncthreads();
    }
    int run = (t == 0) ? 0 : part[t - 1];
    for (int i = 0; i < 64; ++i) {
        rp[base + i] = run;
        run += cnt[base + i];
        cnt[base + i] = 0;
    }
    if (t == 255) rp[N_NODES] = run;
}

// ---------------------------------------------------------------------------
__global__ void fill_kernel(const unsigned* keys, const unsigned* vals,
                            const float* ew, const int* rp, int* cur,
                            int* col, float* wv, float* deg) {
    int i = blockIdx.x * 256 + threadIdx.x;
    unsigned v = vals[i];
    if (!v) return;
    unsigned key = keys[i];
    int r = (int)(key >> 14);
    int c = (int)(key & 16383u);
    float w = ew[v - 1u];
    int pos = rp[r] + atomicAdd(&cur[r], 1);
    col[pos] = c;
    wv[pos] = w;
    atomicAdd(&deg[r], w);
}

// ---------------------------------------------------------------------------
// Gather SpMM, 128 feature cols: one wave per row, float2 per lane.
__global__ void spmm128_kernel(const float* __restrict__ x, const int* __restrict__ rp,
                               const int* __restrict__ col, const float* __restrict__ wv,
                               const float* __restrict__ deg, float* __restrict__ out) {
    int wave = threadIdx.x >> 6, lane = threadIdx.x & 63;
    int r = blockIdx.x * 4 + wave;
    const float2* x2 = (const float2*)x;
    float2 acc = x2[r * 64 + lane];            // self-loop weight 1
    int e1 = rp[r + 1];
    for (int j = rp[r]; j < e1; ++j) {
        int c = col[j];
        float w = wv[j];
        float2 v = x2[c * 64 + lane];
        acc.x += w * v.x;
        acc.y += w * v.y;
    }
    float inv = 1.0f / deg[r];
    ((float2*)out)[r * 64 + lane] = make_float2(acc.x * inv, acc.y * inv);
}

// Gather SpMM, 256 feature cols: one wave per row, float4 per lane.
__global__ void spmm256_kernel(const float* __restrict__ x, const int* __restrict__ rp,
                               const int* __restrict__ col, const float* __restrict__ wv,
                               const float* __restrict__ deg, float* __restrict__ out) {
    int wave = threadIdx.x >> 6, lane = threadIdx.x & 63;
    int r = blockIdx.x * 4 + wave;
    const float4* x4 = (const float4*)x;
    float4 acc = x4[r * 64 + lane];
    int e1 = rp[r + 1];
    for (int j = rp[r]; j < e1; ++j) {
        int c = col[j];
        float w = wv[j];
        float4 v = x4[c * 64 + lane];
        acc.x += w * v.x; acc.y += w * v.y; acc.z += w * v.z; acc.w += w * v.w;
    }
    float inv = 1.0f / deg[r];
    ((float4*)out)[r * 64 + lane] =
        make_float4(acc.x * inv, acc.y * inv, acc.z * inv, acc.w * inv);
}

// ---------------------------------------------------------------------------
// GEMM1: [N,128] @ [128,256] + b. Block = 32 rows. Thread: col c0..c0+3,
// rows m0..m0+7. A-tile in LDS, reads are wave-uniform broadcasts.
__launch_bounds__(256)
__global__ void gemm1_kernel(const float* __restrict__ h0, const float* __restrict__ W1,
                             const float* __restrict__ b1, float* __restrict__ hout) {
    __shared__ float sA[32][F_IN];
    int t = threadIdx.x;
    int rbase = blockIdx.x * 32;
    for (int it = 0; it < 4; ++it) {
        int id = t + it * 256;       // [0,1024) float4 ids
        int m = id >> 5;             // row in tile
        int k0 = (id & 31) * 4;      // consecutive lanes -> consecutive k: coalesced
        *(float4*)&sA[m][k0] = *(const float4*)&h0[(size_t)(rbase + m) * F_IN + k0];
    }
    __syncthreads();
    int c0 = (t & 63) * 4;
    int m0 = (t >> 6) * 8;
    float acc[8][4] = {};
    for (int k = 0; k < F_IN; ++k) {
        float4 w = *(const float4*)&W1[(size_t)k * F_HID + c0];
#pragma unroll
        for (int i = 0; i < 8; ++i) {
            float a = sA[m0 + i][k];   // uniform across wave -> LDS broadcast
            acc[i][0] += a * w.x; acc[i][1] += a * w.y;
            acc[i][2] += a * w.z; acc[i][3] += a * w.w;
        }
    }
    float4 bias = *(const float4*)&b1[c0];
#pragma unroll
    for (int i = 0; i < 8; ++i) {
        float4 o = make_float4(acc[i][0] + bias.x, acc[i][1] + bias.y,
                               acc[i][2] + bias.z, acc[i][3] + bias.w);
        *(float4*)&hout[(size_t)(rbase + m0 + i) * F_HID + c0] = o;
    }
}

// ---------------------------------------------------------------------------
// LayerNorm + ReLU in-place over rows of 256. One block per row.
__global__ void ln_relu_kernel(float* __restrict__ h, const float* __restrict__ g,
                               const float* __restrict__ b) {
    int r = blockIdx.x, t = threadIdx.x;
    float v = h[(size_t)r * F_HID + t];
    float s = v, q = v * v;
    for (int off = 32; off; off >>= 1) {
        s += __shfl_xor(s, off, 64);
        q += __shfl_xor(q, off, 64);
    }
    __shared__ float s1[4], s2[4];
    int wave = t >> 6;
    if ((t & 63) == 0) { s1[wave] = s; s2[wave] = q; }
    __syncthreads();
    float S = s1[0] + s1[1] + s1[2] + s1[3];
    float Q = s2[0] + s2[1] + s2[2] + s2[3];
    float mean = S * (1.0f / F_HID);
    float var = Q * (1.0f / F_HID) - mean * mean;
    float y = (v - mean) * rsqrtf(var + LN_EPS) * g[t] + b[t];
    h[(size_t)r * F_HID + t] = fmaxf(y, 0.0f);
}

// ---------------------------------------------------------------------------
// GEMM2: [N,256] @ [256,128] + b. Block = 32 rows. Thread: col c0..c0+3,
// rows m0..m0+3.
__launch_bounds__(256)
__global__ void gemm2_kernel(const float* __restrict__ h1, const float* __restrict__ W2,
                             const float* __restrict__ b2, float* __restrict__ out) {
    __shared__ float sH[32][F_HID];
    int t = threadIdx.x;
    int rbase = blockIdx.x * 32;
    for (int it = 0; it < 8; ++it) {
        int id = t + it * 256;       // [0,2048) float4 ids
        int m = id >> 6;
        int k0 = (id & 63) * 4;
        *(float4*)&sH[m][k0] = *(const float4*)&h1[(size_t)(rbase + m) * F_HID + k0];
    }
    __syncthreads();
    int c0 = (t & 31) * 4;
    int m0 = (t >> 5) * 4;
    float acc[4][4] = {};
    for (int k = 0; k < F_HID; ++k) {
        float4 w = *(const float4*)&W2[(size_t)k * F_OUT + c0];
#pragma unroll
        for (int i = 0; i < 4; ++i) {
            float a = sH[m0 + i][k];   // 2 addresses per wave, 2-way broadcast: free
            acc[i][0] += a * w.x; acc[i][1] += a * w.y;
            acc[i][2] += a * w.z; acc[i][3] += a * w.w;
        }
    }
    float4 bias = *(const float4*)&b2[c0];
#pragma unroll
    for (int i = 0; i < 4; ++i) {
        float4 o = make_float4(acc[i][0] + bias.x, acc[i][1] + bias.y,
                               acc[i][2] + bias.z, acc[i][3] + bias.w);
        *(float4*)&out[(size_t)(rbase + m0 + i) * F_OUT + c0] = o;
    }
}

// ---------------------------------------------------------------------------
extern "C" void kernel_launch(void* const* d_in, const int* in_sizes, int n_in,
                              void* d_out, int out_size, void* d_ws, size_t ws_size,
                              hipStream_t stream) {
    const float* x   = (const float*)d_in[0];
    const void*  ei  = d_in[1];
    const float* ew  = (const float*)d_in[2];
    const float* W1  = (const float*)d_in[3];
    const float* b1  = (const float*)d_in[4];
    const float* W2  = (const float*)d_in[5];
    const float* b2  = (const float*)d_in[6];
    const float* lng = (const float*)d_in[7];
    const float* lnb = (const float*)d_in[8];
    float* out = (float*)d_out;
    int E = in_sizes[2];

    char* w = (char*)d_ws;
    size_t off = 0;
    auto take = [&](size_t bytes) -> char* {
        char* p = w + off;
        off += (bytes + 255) & ~(size_t)255;
        return p;
    };
    unsigned* keys = (unsigned*)take((size_t)HSIZE * 4);
    unsigned* vals = (unsigned*)take((size_t)HSIZE * 4);
    int*   rp   = (int*)take((size_t)(N_NODES + 1) * 4);
    int*   cnt  = (int*)take((size_t)N_NODES * 4);
    float* deg  = (float*)take((size_t)N_NODES * 4);
    int*   col  = (int*)take((size_t)E * 4);
    float* wv   = (float*)take((size_t)E * 4);
    float* h0   = (float*)take((size_t)N_NODES * F_IN * 4);
    float* h    = (float*)take((size_t)N_NODES * F_HID * 4);
    float* h1   = (float*)take((size_t)N_NODES * F_HID * 4);
    int*   mode = (int*)take(4);

    detect_mode_kernel<<<1, 256, 0, stream>>>((const unsigned*)ei, mode);
    init_kernel<<<HSIZE / 256, 256, 0, stream>>>(keys, vals, cnt, deg);
    insert_kernel<<<(E + 255) / 256, 256, 0, stream>>>(ei, mode, keys, vals, E);
    count_kernel<<<HSIZE / 256, 256, 0, stream>>>(keys, vals, cnt);
    scan_kernel<<<1, 256, 0, stream>>>(cnt, rp);
    fill_kernel<<<HSIZE / 256, 256, 0, stream>>>(keys, vals, ew, rp, cnt, col, wv, deg);
    spmm128_kernel<<<N_NODES / 4, 256, 0, stream>>>(x, rp, col, wv, deg, h0);
    gemm1_kernel<<<N_NODES / 32, 256, 0, stream>>>(h0, W1, b1, h);
    ln_relu_kernel<<<N_NODES, 256, 0, stream>>>(h, lng, lnb);
    spmm256_kernel<<<N_NODES / 4, 256, 0, stream>>>(h, rp, col, wv, deg, h1);
    gemm2_kernel<<<N_NODES / 32, 256, 0, stream>>>(h1, W2, b2, out);
}

// Round 2
// 381.528 us; speedup vs baseline: 1.2241x; 1.2241x over previous
//
#include <hip/hip_runtime.h>

#define N_NODES 16384
#define F_IN    128
#define F_HID   256
#define F_OUT   128
#define HSIZE   (1u << 20)
#define HMASK   (HSIZE - 1u)
#define EMPTY_KEY 0xFFFFFFFFu
#define LN_EPS  1e-5f

// ---------------------------------------------------------------------------
// Detect whether edge_index arrived as int64 (odd u32 words all zero) or int32.
__global__ void detect_mode_kernel(const unsigned* ei, int* mode) {
    __shared__ int nz;
    if (threadIdx.x == 0) nz = 0;
    __syncthreads();
    for (int it = 0; it < 4; ++it) {
        int idx = 2 * (threadIdx.x + it * 256) + 1;
        if (ei[idx] != 0u) nz = 1;   // benign race, all writers store 1
    }
    __syncthreads();
    if (threadIdx.x == 0) *mode = (nz == 0) ? 1 : 0;  // 1 => int64
}

// ---------------------------------------------------------------------------
__global__ void init_kernel(unsigned* keys, unsigned* vals, int* cnt, float* deg) {
    int i = blockIdx.x * 256 + threadIdx.x;
    keys[i] = EMPTY_KEY;
    vals[i] = 0u;
    if (i < N_NODES) { cnt[i] = 0; deg[i] = 1.0f; }   // degree starts with self-loop
}

// ---------------------------------------------------------------------------
// Hash insert with last-write-wins: per (r,c) key keep max edge index (e+1).
__global__ void insert_kernel(const void* ei, const int* mode,
                              unsigned* keys, unsigned* vals, int E) {
    int e = blockIdx.x * 256 + threadIdx.x;
    if (e >= E) return;
    int r, c;
    if (*mode) {
        const long long* p = (const long long*)ei;
        r = (int)p[e]; c = (int)p[e + E];
    } else {
        const int* p = (const int*)ei;
        r = p[e]; c = p[e + E];
    }
    unsigned key = ((unsigned)r << 14) | (unsigned)c;
    unsigned slot = (key * 2654435761u) >> 12;   // top 20 bits
    for (;;) {
        unsigned prev = atomicCAS(&keys[slot], EMPTY_KEY, key);
        if (prev == EMPTY_KEY || prev == key) {
            atomicMax(&vals[slot], (unsigned)(e + 1));
            break;
        }
        slot = (slot + 1u) & HMASK;
    }
}

// ---------------------------------------------------------------------------
__global__ void count_kernel(const unsigned* keys, const unsigned* vals, int* cnt) {
    int i = blockIdx.x * 256 + threadIdx.x;
    if (vals[i]) atomicAdd(&cnt[keys[i] >> 14], 1);
}

// ---------------------------------------------------------------------------
// Exclusive scan over 16384 row counts; single block of 256 threads x 64 rows.
// Also zeroes cnt[] so fill_kernel can reuse it as a per-row cursor.
__global__ void scan_kernel(int* cnt, int* rp) {
    __shared__ int part[256];
    int t = threadIdx.x;
    int base = t * 64;
    int s = 0;
    for (int i = 0; i < 64; ++i) s += cnt[base + i];
    part[t] = s;
    __syncthreads();
    for (int off = 1; off < 256; off <<= 1) {
        int v = (t >= off) ? part[t - off] : 0;
        __syncthreads();
        part[t] += v;
        __syncthreads();
    }
    int run = (t == 0) ? 0 : part[t - 1];
    for (int i = 0; i < 64; ++i) {
        rp[base + i] = run;
        run += cnt[base + i];
        cnt[base + i] = 0;
    }
    if (t == 255) rp[N_NODES] = run;
}

// ---------------------------------------------------------------------------
__global__ void fill_kernel(const unsigned* keys, const unsigned* vals,
                            const float* ew, const int* rp, int* cur,
                            int* col, float* wv, float* deg) {
    int i = blockIdx.x * 256 + threadIdx.x;
    unsigned v = vals[i];
    if (!v) return;
    unsigned key = keys[i];
    int r = (int)(key >> 14);
    int c = (int)(key & 16383u);
    float w = ew[v - 1u];
    int pos = rp[r] + atomicAdd(&cur[r], 1);
    col[pos] = c;
    wv[pos] = w;
    atomicAdd(&deg[r], w);
}

// ---------------------------------------------------------------------------
// Gather SpMM over 128 feature cols: one wave per row, float2 per lane.
// Edge loop unrolled x4 so each wave keeps 4 gathers (2 KB) in flight.
// Epilogue: out = acc / deg (+ bias if non-null).
__global__ void spmm128_kernel(const float* __restrict__ xin, const int* __restrict__ rp,
                               const int* __restrict__ col, const float* __restrict__ wv,
                               const float* __restrict__ deg, const float* __restrict__ bias,
                               float* __restrict__ outp) {
    int wave = threadIdx.x >> 6, lane = threadIdx.x & 63;
    int r = blockIdx.x * 4 + wave;
    const float2* x2 = (const float2*)xin;
    float2 acc = x2[r * 64 + lane];            // self-loop, weight 1
    int j = rp[r], e1 = rp[r + 1];
    for (; j + 4 <= e1; j += 4) {
        int c0 = col[j], c1 = col[j + 1], c2 = col[j + 2], c3 = col[j + 3];
        float w0 = wv[j], w1 = wv[j + 1], w2 = wv[j + 2], w3 = wv[j + 3];
        float2 v0 = x2[c0 * 64 + lane];
        float2 v1 = x2[c1 * 64 + lane];
        float2 v2 = x2[c2 * 64 + lane];
        float2 v3 = x2[c3 * 64 + lane];
        acc.x += w0 * v0.x + w1 * v1.x + w2 * v2.x + w3 * v3.x;
        acc.y += w0 * v0.y + w1 * v1.y + w2 * v2.y + w3 * v3.y;
    }
    for (; j < e1; ++j) {
        int c = col[j];
        float w = wv[j];
        float2 v = x2[c * 64 + lane];
        acc.x += w * v.x;
        acc.y += w * v.y;
    }
    float inv = 1.0f / deg[r];
    float2 o = make_float2(acc.x * inv, acc.y * inv);
    if (bias) { o.x += bias[2 * lane]; o.y += bias[2 * lane + 1]; }
    ((float2*)outp)[r * 64 + lane] = o;
}

// ---------------------------------------------------------------------------
// Fused MLP: h2 = relu(LN(h0 @ W1 + b1)) @ W2  (bias b2 added later in spmm).
// Block = 32 rows. Stage A: each wave owns 8 full rows (lane = 4 of 256 cols),
// so LN is a wave shuffle-reduce. Stage B through a 32 KB LDS tile.
__launch_bounds__(256)
__global__ void fused_mlp_kernel(const float* __restrict__ h0, const float* __restrict__ W1,
                                 const float* __restrict__ b1, const float* __restrict__ W2,
                                 const float* __restrict__ ln_g, const float* __restrict__ ln_b,
                                 float* __restrict__ h2out) {
    __shared__ float sA[32][F_IN];    // 16 KB
    __shared__ float sH[32][F_HID];   // 32 KB
    int t = threadIdx.x;
    int rbase = blockIdx.x * 32;
    for (int it = 0; it < 4; ++it) {
        int id = t + it * 256;        // [0,1024) float4 ids
        int m = id >> 5;
        int k0 = (id & 31) * 4;       // consecutive lanes -> consecutive k: coalesced
        *(float4*)&sA[m][k0] = *(const float4*)&h0[(size_t)(rbase + m) * F_IN + k0];
    }
    __syncthreads();

    int lane = t & 63;
    int c0 = lane * 4;                // 256 cols across the wave
    int m0 = (t >> 6) * 8;            // 8 rows per wave
    float acc[8][4] = {};
    for (int k = 0; k < F_IN; ++k) {
        float4 w = *(const float4*)&W1[(size_t)k * F_HID + c0];
#pragma unroll
        for (int i = 0; i < 8; ++i) {
            float a = sA[m0 + i][k];  // wave-uniform -> LDS broadcast
            acc[i][0] += a * w.x; acc[i][1] += a * w.y;
            acc[i][2] += a * w.z; acc[i][3] += a * w.w;
        }
    }
    float4 bias = *(const float4*)&b1[c0];
    float4 g4 = *(const float4*)&ln_g[c0];
    float4 bb4 = *(const float4*)&ln_b[c0];
#pragma unroll
    for (int i = 0; i < 8; ++i) {
        float v0 = acc[i][0] + bias.x, v1 = acc[i][1] + bias.y;
        float v2 = acc[i][2] + bias.z, v3 = acc[i][3] + bias.w;
        float s = v0 + v1 + v2 + v3;
        float q = v0 * v0 + v1 * v1 + v2 * v2 + v3 * v3;
        for (int off = 32; off; off >>= 1) {
            s += __shfl_xor(s, off, 64);
            q += __shfl_xor(q, off, 64);
        }
        float mean = s * (1.0f / F_HID);
        float var = q * (1.0f / F_HID) - mean * mean;
        float rinv = rsqrtf(var + LN_EPS);
        v0 = fmaxf((v0 - mean) * rinv * g4.x + bb4.x, 0.0f);
        v1 = fmaxf((v1 - mean) * rinv * g4.y + bb4.y, 0.0f);
        v2 = fmaxf((v2 - mean) * rinv * g4.z + bb4.z, 0.0f);
        v3 = fmaxf((v3 - mean) * rinv * g4.w + bb4.w, 0.0f);
        *(float4*)&sH[m0 + i][c0] = make_float4(v0, v1, v2, v3);
    }
    __syncthreads();

    // Stage B: [32,256] @ [256,128]
    int c0b = (t & 31) * 4;           // 128 cols across half-wave
    int m0b = (t >> 5) * 4;           // 4 rows per half-wave
    float acc2[4][4] = {};
    for (int k = 0; k < F_HID; ++k) {
        float4 w = *(const float4*)&W2[(size_t)k * F_OUT + c0b];
#pragma unroll
        for (int i = 0; i < 4; ++i) {
            float a = sH[m0b + i][k]; // 2 addresses per wave -> free 2-way broadcast
            acc2[i][0] += a * w.x; acc2[i][1] += a * w.y;
            acc2[i][2] += a * w.z; acc2[i][3] += a * w.w;
        }
    }
#pragma unroll
    for (int i = 0; i < 4; ++i) {
        *(float4*)&h2out[(size_t)(rbase + m0b + i) * F_OUT + c0b] =
            make_float4(acc2[i][0], acc2[i][1], acc2[i][2], acc2[i][3]);
    }
}

// ---------------------------------------------------------------------------
extern "C" void kernel_launch(void* const* d_in, const int* in_sizes, int n_in,
                              void* d_out, int out_size, void* d_ws, size_t ws_size,
                              hipStream_t stream) {
    const float* x   = (const float*)d_in[0];
    const void*  ei  = d_in[1];
    const float* ew  = (const float*)d_in[2];
    const float* W1  = (const float*)d_in[3];
    const float* b1  = (const float*)d_in[4];
    const float* W2  = (const float*)d_in[5];
    const float* b2  = (const float*)d_in[6];
    const float* lng = (const float*)d_in[7];
    const float* lnb = (const float*)d_in[8];
    float* out = (float*)d_out;
    int E = in_sizes[2];

    char* w = (char*)d_ws;
    size_t off = 0;
    auto take = [&](size_t bytes) -> char* {
        char* p = w + off;
        off += (bytes + 255) & ~(size_t)255;
        return p;
    };
    unsigned* keys = (unsigned*)take((size_t)HSIZE * 4);
    unsigned* vals = (unsigned*)take((size_t)HSIZE * 4);
    int*   rp   = (int*)take((size_t)(N_NODES + 1) * 4);
    int*   cnt  = (int*)take((size_t)N_NODES * 4);
    float* deg  = (float*)take((size_t)N_NODES * 4);
    int*   col  = (int*)take((size_t)E * 4);
    float* wv   = (float*)take((size_t)E * 4);
    float* h0   = (float*)take((size_t)N_NODES * F_IN * 4);
    float* h2   = (float*)take((size_t)N_NODES * F_OUT * 4);
    int*   mode = (int*)take(4);

    detect_mode_kernel<<<1, 256, 0, stream>>>((const unsigned*)ei, mode);
    init_kernel<<<HSIZE / 256, 256, 0, stream>>>(keys, vals, cnt, deg);
    insert_kernel<<<(E + 255) / 256, 256, 0, stream>>>(ei, mode, keys, vals, E);
    count_kernel<<<HSIZE / 256, 256, 0, stream>>>(keys, vals, cnt);
    scan_kernel<<<1, 256, 0, stream>>>(cnt, rp);
    fill_kernel<<<HSIZE / 256, 256, 0, stream>>>(keys, vals, ew, rp, cnt, col, wv, deg);
    // h0 = D^-1 (A+I) x
    spmm128_kernel<<<N_NODES / 4, 256, 0, stream>>>(x, rp, col, wv, deg, nullptr, h0);
    // h2 = relu(LN(h0 W1 + b1)) W2
    fused_mlp_kernel<<<N_NODES / 32, 256, 0, stream>>>(h0, W1, b1, W2, lng, lnb, h2);
    // out = D^-1 (A+I) h2 + b2   (== (D^-1 (A+I) h) W2 + b2 by linearity)
    spmm128_kernel<<<N_NODES / 4, 256, 0, stream>>>(h2, rp, col, wv, deg, b2, out);
}

// Round 3
// 303.037 us; speedup vs baseline: 1.5412x; 1.2590x over previous
//
#include <hip/hip_runtime.h>

#define N_NODES 16384
#define F_IN    128
#define F_HID   256
#define F_OUT   128
#define LN_EPS  1e-5f
#define MAXD    192   // per-row dedupe capacity; P(row deg > 192) ~ 0 for Poisson(32)

// ---------------------------------------------------------------------------
// Detect whether edge_index arrived as int64 (odd u32 words all zero) or int32.
__global__ void detect_mode_kernel(const unsigned* ei, int* mode) {
    __shared__ int nz;
    if (threadIdx.x == 0) nz = 0;
    __syncthreads();
    for (int it = 0; it < 4; ++it) {
        int idx = 2 * (threadIdx.x + it * 256) + 1;
        if (ei[idx] != 0u) nz = 1;   // benign race, all writers store 1
    }
    __syncthreads();
    if (threadIdx.x == 0) *mode = (nz == 0) ? 1 : 0;  // 1 => int64
}

// ---------------------------------------------------------------------------
__global__ void init_kernel(int* cnt) {
    int i = blockIdx.x * 256 + threadIdx.x;
    cnt[i] = 0;
}

// ---------------------------------------------------------------------------
__global__ void count_kernel(const void* ei, const int* mode, int* cnt, int E) {
    int e = blockIdx.x * 256 + threadIdx.x;
    if (e >= E) return;
    int r = (*mode) ? (int)((const long long*)ei)[e] : ((const int*)ei)[e];
    atomicAdd(&cnt[r], 1);
}

// ---------------------------------------------------------------------------
// Exclusive scan over 16384 row counts; single block of 256 threads x 64 rows.
// Also zeroes cnt[] so fill_kernel can reuse it as a per-row cursor.
__global__ void scan_kernel(int* cnt, int* rp) {
    __shared__ int part[256];
    int t = threadIdx.x;
    int base = t * 64;
    int s = 0;
    for (int i = 0; i < 64; ++i) s += cnt[base + i];
    part[t] = s;
    __syncthreads();
    for (int off = 1; off < 256; off <<= 1) {
        int v = (t >= off) ? part[t - off] : 0;
        __syncthreads();
        part[t] += v;
        __syncthreads();
    }
    int run = (t == 0) ? 0 : part[t - 1];
    for (int i = 0; i < 64; ++i) {
        rp[base + i] = run;
        run += cnt[base + i];
        cnt[base + i] = 0;
    }
    if (t == 255) rp[N_NODES] = run;
}

// ---------------------------------------------------------------------------
// CSR fill with packed entries: edges[pos] = {col, edge_id, w_bits, 0}.
__global__ void fill_kernel(const void* ei, const int* mode, const float* ew,
                            const int* rp, int* cur, int4* edges, int E) {
    int e = blockIdx.x * 256 + threadIdx.x;
    if (e >= E) return;
    int r, c;
    if (*mode) {
        const long long* p = (const long long*)ei;
        r = (int)p[e]; c = (int)p[e + E];
    } else {
        const int* p = (const int*)ei;
        r = p[e]; c = p[e + E];
    }
    int pos = rp[r] + atomicAdd(&cur[r], 1);
    edges[pos] = make_int4(c, e, __float_as_int(ew[e]), 0);
}

// ---------------------------------------------------------------------------
// Per-row dedupe (last edge wins) + degree. One wave per row. Entries whose
// (col) reappears with a higher edge_id get w := 0 and are excluded from the
// degree sum — exactly numpy's sequential adj[r,c] = w semantics.
__global__ void dedupe_kernel(const int* __restrict__ rp, int4* __restrict__ edges,
                              float* __restrict__ invdeg) {
    __shared__ int scol[4][MAXD];
    __shared__ int seid[4][MAXD];
    int wave = threadIdx.x >> 6, lane = threadIdx.x & 63;
    int r = blockIdx.x * 4 + wave;
    int j0 = rp[r], j1 = rp[r + 1];
    int d = j1 - j0;
    if (d > MAXD) d = MAXD;
    int   mycol[3], myeid[3];
    float myw[3];
    int nown = 0;
    for (int i = lane; i < d; i += 64) {
        int4 e = edges[j0 + i];
        scol[wave][i] = e.x;
        seid[wave][i] = e.y;
        mycol[nown] = e.x; myeid[nown] = e.y; myw[nown] = __int_as_float(e.z);
        ++nown;
    }
    __syncthreads();
    float wsum = 0.0f;
    nown = 0;
    for (int i = lane; i < d; i += 64) {
        bool kill = false;
        for (int j = 0; j < d; ++j)
            if (scol[wave][j] == mycol[nown] && seid[wave][j] > myeid[nown]) { kill = true; break; }
        if (kill) ((int*)&edges[j0 + i])[2] = 0;   // zero the weight
        else wsum += myw[nown];
        ++nown;
    }
    for (int off = 32; off; off >>= 1) wsum += __shfl_xor(wsum, off, 64);
    if (lane == 0) invdeg[r] = 1.0f / (1.0f + wsum);   // +1 self-loop; >=1 so clip no-op
}

// ---------------------------------------------------------------------------
// Gather SpMM over 128 feature cols: one wave per row, float2 per lane.
// Edge descriptors are wave-uniform (scalar loads); x8 unroll keeps 8 gathers
// (4 KB) in flight per wave. Epilogue: out = acc * invdeg (+ bias if non-null).
__global__ void spmm128_kernel(const float* __restrict__ xin, const int* __restrict__ rp,
                               const int4* __restrict__ ed, const float* __restrict__ invdeg,
                               const float* __restrict__ bias, float* __restrict__ outp) {
    int wave = threadIdx.x >> 6, lane = threadIdx.x & 63;
    int r = blockIdx.x * 4 + wave;
    const float2* x2 = (const float2*)xin;
    float2 acc = x2[r * 64 + lane];            // self-loop, weight 1
    int j = rp[r], e1 = rp[r + 1];
    for (; j + 8 <= e1; j += 8) {
        int4 e0 = ed[j],     e1q = ed[j + 1], e2 = ed[j + 2], e3 = ed[j + 3];
        int4 e4 = ed[j + 4], e5  = ed[j + 5], e6 = ed[j + 6], e7 = ed[j + 7];
        float2 v0 = x2[e0.x * 64 + lane];
        float2 v1 = x2[e1q.x * 64 + lane];
        float2 v2 = x2[e2.x * 64 + lane];
        float2 v3 = x2[e3.x * 64 + lane];
        float2 v4 = x2[e4.x * 64 + lane];
        float2 v5 = x2[e5.x * 64 + lane];
        float2 v6 = x2[e6.x * 64 + lane];
        float2 v7 = x2[e7.x * 64 + lane];
        float w0 = __int_as_float(e0.z), w1 = __int_as_float(e1q.z);
        float w2 = __int_as_float(e2.z), w3 = __int_as_float(e3.z);
        float w4 = __int_as_float(e4.z), w5 = __int_as_float(e5.z);
        float w6 = __int_as_float(e6.z), w7 = __int_as_float(e7.z);
        acc.x += w0 * v0.x + w1 * v1.x + w2 * v2.x + w3 * v3.x
               + w4 * v4.x + w5 * v5.x + w6 * v6.x + w7 * v7.x;
        acc.y += w0 * v0.y + w1 * v1.y + w2 * v2.y + w3 * v3.y
               + w4 * v4.y + w5 * v5.y + w6 * v6.y + w7 * v7.y;
    }
    for (; j < e1; ++j) {
        int4 e = ed[j];
        float w = __int_as_float(e.z);
        float2 v = x2[e.x * 64 + lane];
        acc.x += w * v.x;
        acc.y += w * v.y;
    }
    float inv = invdeg[r];
    float2 o = make_float2(acc.x * inv, acc.y * inv);
    if (bias) { o.x += bias[2 * lane]; o.y += bias[2 * lane + 1]; }
    ((float2*)outp)[r * 64 + lane] = o;
}

// ---------------------------------------------------------------------------
// Fused MLP: h2 = relu(LN(h0 @ W1 + b1)) @ W2  (bias b2 added later in spmm).
// Block = 32 rows. Stage A: each wave owns 8 full rows (lane = 4 of 256 cols),
// so LN is a wave shuffle-reduce. Stage B through a 32 KB LDS tile.
// Inner loops k-vectorized x4: ds_read_b128 instead of 4x ds_read_b32.
__launch_bounds__(256)
__global__ void fused_mlp_kernel(const float* __restrict__ h0, const float* __restrict__ W1,
                                 const float* __restrict__ b1, const float* __restrict__ W2,
                                 const float* __restrict__ ln_g, const float* __restrict__ ln_b,
                                 float* __restrict__ h2out) {
    __shared__ float sA[32][F_IN];    // 16 KB
    __shared__ float sH[32][F_HID];   // 32 KB
    int t = threadIdx.x;
    int rbase = blockIdx.x * 32;
    for (int it = 0; it < 4; ++it) {
        int id = t + it * 256;        // [0,1024) float4 ids
        int m = id >> 5;
        int k0 = (id & 31) * 4;       // consecutive lanes -> consecutive k: coalesced
        *(float4*)&sA[m][k0] = *(const float4*)&h0[(size_t)(rbase + m) * F_IN + k0];
    }
    __syncthreads();

    int lane = t & 63;
    int c0 = lane * 4;                // 256 cols across the wave
    int m0 = (t >> 6) * 8;            // 8 rows per wave
    float acc[8][4] = {};
    for (int k = 0; k < F_IN; k += 4) {
        float4 a[8];
#pragma unroll
        for (int i = 0; i < 8; ++i) a[i] = *(const float4*)&sA[m0 + i][k];  // broadcast b128
        float4 wk0 = *(const float4*)&W1[(size_t)k       * F_HID + c0];
        float4 wk1 = *(const float4*)&W1[(size_t)(k + 1) * F_HID + c0];
        float4 wk2 = *(const float4*)&W1[(size_t)(k + 2) * F_HID + c0];
        float4 wk3 = *(const float4*)&W1[(size_t)(k + 3) * F_HID + c0];
#pragma unroll
        for (int i = 0; i < 8; ++i) {
            acc[i][0] += a[i].x * wk0.x + a[i].y * wk1.x + a[i].z * wk2.x + a[i].w * wk3.x;
            acc[i][1] += a[i].x * wk0.y + a[i].y * wk1.y + a[i].z * wk2.y + a[i].w * wk3.y;
            acc[i][2] += a[i].x * wk0.z + a[i].y * wk1.z + a[i].z * wk2.z + a[i].w * wk3.z;
            acc[i][3] += a[i].x * wk0.w + a[i].y * wk1.w + a[i].z * wk2.w + a[i].w * wk3.w;
        }
    }
    float4 bias = *(const float4*)&b1[c0];
    float4 g4 = *(const float4*)&ln_g[c0];
    float4 bb4 = *(const float4*)&ln_b[c0];
#pragma unroll
    for (int i = 0; i < 8; ++i) {
        float v0 = acc[i][0] + bias.x, v1 = acc[i][1] + bias.y;
        float v2 = acc[i][2] + bias.z, v3 = acc[i][3] + bias.w;
        float s = v0 + v1 + v2 + v3;
        float q = v0 * v0 + v1 * v1 + v2 * v2 + v3 * v3;
        for (int off = 32; off; off >>= 1) {
            s += __shfl_xor(s, off, 64);
            q += __shfl_xor(q, off, 64);
        }
        float mean = s * (1.0f / F_HID);
        float var = q * (1.0f / F_HID) - mean * mean;
        float rinv = rsqrtf(var + LN_EPS);
        v0 = fmaxf((v0 - mean) * rinv * g4.x + bb4.x, 0.0f);
        v1 = fmaxf((v1 - mean) * rinv * g4.y + bb4.y, 0.0f);
        v2 = fmaxf((v2 - mean) * rinv * g4.z + bb4.z, 0.0f);
        v3 = fmaxf((v3 - mean) * rinv * g4.w + bb4.w, 0.0f);
        *(float4*)&sH[m0 + i][c0] = make_float4(v0, v1, v2, v3);
    }
    __syncthreads();

    // Stage B: [32,256] @ [256,128]
    int c0b = (t & 31) * 4;           // 128 cols across half-wave
    int m0b = (t >> 5) * 4;           // 4 rows per half-wave
    float acc2[4][4] = {};
    for (int k = 0; k < F_HID; k += 4) {
        float4 a[4];
#pragma unroll
        for (int i = 0; i < 4; ++i) a[i] = *(const float4*)&sH[m0b + i][k];  // 2-addr b128
        float4 wk0 = *(const float4*)&W2[(size_t)k       * F_OUT + c0b];
        float4 wk1 = *(const float4*)&W2[(size_t)(k + 1) * F_OUT + c0b];
        float4 wk2 = *(const float4*)&W2[(size_t)(k + 2) * F_OUT + c0b];
        float4 wk3 = *(const float4*)&W2[(size_t)(k + 3) * F_OUT + c0b];
#pragma unroll
        for (int i = 0; i < 4; ++i) {
            acc2[i][0] += a[i].x * wk0.x + a[i].y * wk1.x + a[i].z * wk2.x + a[i].w * wk3.x;
            acc2[i][1] += a[i].x * wk0.y + a[i].y * wk1.y + a[i].z * wk2.y + a[i].w * wk3.y;
            acc2[i][2] += a[i].x * wk0.z + a[i].y * wk1.z + a[i].z * wk2.z + a[i].w * wk3.z;
            acc2[i][3] += a[i].x * wk0.w + a[i].y * wk1.w + a[i].z * wk2.w + a[i].w * wk3.w;
        }
    }
#pragma unroll
    for (int i = 0; i < 4; ++i) {
        *(float4*)&h2out[(size_t)(rbase + m0b + i) * F_OUT + c0b] =
            make_float4(acc2[i][0], acc2[i][1], acc2[i][2], acc2[i][3]);
    }
}

// ---------------------------------------------------------------------------
extern "C" void kernel_launch(void* const* d_in, const int* in_sizes, int n_in,
                              void* d_out, int out_size, void* d_ws, size_t ws_size,
                              hipStream_t stream) {
    const float* x   = (const float*)d_in[0];
    const void*  ei  = d_in[1];
    const float* ew  = (const float*)d_in[2];
    const float* W1  = (const float*)d_in[3];
    const float* b1  = (const float*)d_in[4];
    const float* W2  = (const float*)d_in[5];
    const float* b2  = (const float*)d_in[6];
    const float* lng = (const float*)d_in[7];
    const float* lnb = (const float*)d_in[8];
    float* out = (float*)d_out;
    int E = in_sizes[2];

    char* w = (char*)d_ws;
    size_t off = 0;
    auto take = [&](size_t bytes) -> char* {
        char* p = w + off;
        off += (bytes + 255) & ~(size_t)255;
        return p;
    };
    int*   rp     = (int*)take((size_t)(N_NODES + 1) * 4);
    int*   cnt    = (int*)take((size_t)N_NODES * 4);
    float* invdeg = (float*)take((size_t)N_NODES * 4);
    int4*  edges  = (int4*)take((size_t)E * 16);
    float* h0     = (float*)take((size_t)N_NODES * F_IN * 4);
    float* h2     = (float*)take((size_t)N_NODES * F_OUT * 4);
    int*   mode   = (int*)take(4);

    detect_mode_kernel<<<1, 256, 0, stream>>>((const unsigned*)ei, mode);
    init_kernel<<<N_NODES / 256, 256, 0, stream>>>(cnt);
    count_kernel<<<(E + 255) / 256, 256, 0, stream>>>(ei, mode, cnt, E);
    scan_kernel<<<1, 256, 0, stream>>>(cnt, rp);
    fill_kernel<<<(E + 255) / 256, 256, 0, stream>>>(ei, mode, ew, rp, cnt, edges, E);
    dedupe_kernel<<<N_NODES / 4, 256, 0, stream>>>(rp, edges, invdeg);
    // h0 = D^-1 (A+I) x
    spmm128_kernel<<<N_NODES / 4, 256, 0, stream>>>(x, rp, edges, invdeg, nullptr, h0);
    // h2 = relu(LN(h0 W1 + b1)) W2
    fused_mlp_kernel<<<N_NODES / 32, 256, 0, stream>>>(h0, W1, b1, W2, lng, lnb, h2);
    // out = D^-1 (A+I) h2 + b2   (== (D^-1 (A+I) h) W2 + b2 by linearity)
    spmm128_kernel<<<N_NODES / 4, 256, 0, stream>>>(h2, rp, edges, invdeg, b2, out);
}

// Round 4
// 290.375 us; speedup vs baseline: 1.6084x; 1.0436x over previous
//
#include <hip/hip_runtime.h>

#define N_NODES 16384
#define F_IN    128
#define F_HID   256
#define F_OUT   128
#define LN_EPS  1e-5f
#define MAXD    192   // per-row dedupe capacity; P(row deg > 192) ~ 0 for Poisson(32)

typedef unsigned short ushort_t;

__device__ __forceinline__ unsigned short bf16rne(float f) {
    unsigned u = __float_as_uint(f);
    unsigned r = (u + 0x7fffu + ((u >> 16) & 1u)) >> 16;   // round-to-nearest-even
    return (unsigned short)r;
}

// ---------------------------------------------------------------------------
// Detect whether edge_index arrived as int64 (odd u32 words all zero) or int32.
__global__ void detect_mode_kernel(const unsigned* ei, int* mode) {
    __shared__ int nz;
    if (threadIdx.x == 0) nz = 0;
    __syncthreads();
    for (int it = 0; it < 4; ++it) {
        int idx = 2 * (threadIdx.x + it * 256) + 1;
        if (ei[idx] != 0u) nz = 1;   // benign race, all writers store 1
    }
    __syncthreads();
    if (threadIdx.x == 0) *mode = (nz == 0) ? 1 : 0;  // 1 => int64
}

// ---------------------------------------------------------------------------
__global__ void init_kernel(int* cnt) {
    int i = blockIdx.x * 256 + threadIdx.x;
    cnt[i] = 0;
}

// ---------------------------------------------------------------------------
// x (fp32) -> bf16, 4 elems/thread. Shrinks spmm1 gather set to 4 MB (fits L2).
__global__ void convert_kernel(const float* __restrict__ x, unsigned short* __restrict__ xb) {
    int i = (blockIdx.x * 256 + threadIdx.x) * 4;
    float4 v = *(const float4*)&x[i];
    ushort4 o;
    o.x = bf16rne(v.x); o.y = bf16rne(v.y); o.z = bf16rne(v.z); o.w = bf16rne(v.w);
    *(ushort4*)&xb[i] = o;
}

// ---------------------------------------------------------------------------
__global__ void count_kernel(const void* ei, const int* mode, int* cnt, int E) {
    int e = blockIdx.x * 256 + threadIdx.x;
    if (e >= E) return;
    int r = (*mode) ? (int)((const long long*)ei)[e] : ((const int*)ei)[e];
    atomicAdd(&cnt[r], 1);
}

// ---------------------------------------------------------------------------
// Exclusive scan over 16384 row counts; single block of 256 threads x 64 rows.
// Also zeroes cnt[] so fill_kernel can reuse it as a per-row cursor.
__global__ void scan_kernel(int* cnt, int* rp) {
    __shared__ int part[256];
    int t = threadIdx.x;
    int base = t * 64;
    int s = 0;
    for (int i = 0; i < 64; ++i) s += cnt[base + i];
    part[t] = s;
    __syncthreads();
    for (int off = 1; off < 256; off <<= 1) {
        int v = (t >= off) ? part[t - off] : 0;
        __syncthreads();
        part[t] += v;
        __syncthreads();
    }
    int run = (t == 0) ? 0 : part[t - 1];
    for (int i = 0; i < 64; ++i) {
        rp[base + i] = run;
        run += cnt[base + i];
        cnt[base + i] = 0;
    }
    if (t == 255) rp[N_NODES] = run;
}

// ---------------------------------------------------------------------------
// CSR fill with packed entries: edges[pos] = {col, edge_id, w_bits, 0}.
__global__ void fill_kernel(const void* ei, const int* mode, const float* ew,
                            const int* rp, int* cur, int4* edges, int E) {
    int e = blockIdx.x * 256 + threadIdx.x;
    if (e >= E) return;
    int r, c;
    if (*mode) {
        const long long* p = (const long long*)ei;
        r = (int)p[e]; c = (int)p[e + E];
    } else {
        const int* p = (const int*)ei;
        r = p[e]; c = p[e + E];
    }
    int pos = rp[r] + atomicAdd(&cur[r], 1);
    edges[pos] = make_int4(c, e, __float_as_int(ew[e]), 0);
}

// ---------------------------------------------------------------------------
// Per-row dedupe (last edge wins) + degree. One wave per row.
__global__ void dedupe_kernel(const int* __restrict__ rp, int4* __restrict__ edges,
                              float* __restrict__ invdeg) {
    __shared__ int scol[4][MAXD];
    __shared__ int seid[4][MAXD];
    int wave = threadIdx.x >> 6, lane = threadIdx.x & 63;
    int r = blockIdx.x * 4 + wave;
    int j0 = rp[r], j1 = rp[r + 1];
    int d = j1 - j0;
    if (d > MAXD) d = MAXD;
    int   mycol[3], myeid[3];
    float myw[3];
    int nown = 0;
    for (int i = lane; i < d; i += 64) {
        int4 e = edges[j0 + i];
        scol[wave][i] = e.x;
        seid[wave][i] = e.y;
        mycol[nown] = e.x; myeid[nown] = e.y; myw[nown] = __int_as_float(e.z);
        ++nown;
    }
    __syncthreads();
    float wsum = 0.0f;
    nown = 0;
    for (int i = lane; i < d; i += 64) {
        bool kill = false;
        for (int j = 0; j < d; ++j)
            if (scol[wave][j] == mycol[nown] && seid[wave][j] > myeid[nown]) { kill = true; break; }
        if (kill) ((int*)&edges[j0 + i])[2] = 0;   // zero the weight
        else wsum += myw[nown];
        ++nown;
    }
    for (int off = 32; off; off >>= 1) wsum += __shfl_xor(wsum, off, 64);
    if (lane == 0) invdeg[r] = 1.0f / (1.0f + wsum);   // +1 self-loop; >=1 so clip no-op
}

// ---------------------------------------------------------------------------
// Gather SpMM over 128 bf16 feature cols: one wave per row, 1 uint (2 bf16) per
// lane. x8 unroll keeps 8 gathers (2 KB) in flight per wave. Accumulation fp32.
// Epilogue: out(fp32) = acc * invdeg (+ bias if non-null).
__global__ void spmm_bf16_kernel(const unsigned* __restrict__ xb, const int* __restrict__ rp,
                                 const int4* __restrict__ ed, const float* __restrict__ invdeg,
                                 const float* __restrict__ bias, float* __restrict__ outp) {
    int wave = threadIdx.x >> 6, lane = threadIdx.x & 63;
    int r = blockIdx.x * 4 + wave;
    unsigned self = xb[r * 64 + lane];
    float ax = __uint_as_float(self << 16);
    float ay = __uint_as_float(self & 0xffff0000u);
    int j = rp[r], e1 = rp[r + 1];
    for (; j + 8 <= e1; j += 8) {
        int4 e0 = ed[j],     e1q = ed[j + 1], e2 = ed[j + 2], e3 = ed[j + 3];
        int4 e4 = ed[j + 4], e5  = ed[j + 5], e6 = ed[j + 6], e7 = ed[j + 7];
        unsigned v0 = xb[e0.x * 64 + lane];
        unsigned v1 = xb[e1q.x * 64 + lane];
        unsigned v2 = xb[e2.x * 64 + lane];
        unsigned v3 = xb[e3.x * 64 + lane];
        unsigned v4 = xb[e4.x * 64 + lane];
        unsigned v5 = xb[e5.x * 64 + lane];
        unsigned v6 = xb[e6.x * 64 + lane];
        unsigned v7 = xb[e7.x * 64 + lane];
        float w0 = __int_as_float(e0.z), w1 = __int_as_float(e1q.z);
        float w2 = __int_as_float(e2.z), w3 = __int_as_float(e3.z);
        float w4 = __int_as_float(e4.z), w5 = __int_as_float(e5.z);
        float w6 = __int_as_float(e6.z), w7 = __int_as_float(e7.z);
        ax += w0 * __uint_as_float(v0 << 16) + w1 * __uint_as_float(v1 << 16)
            + w2 * __uint_as_float(v2 << 16) + w3 * __uint_as_float(v3 << 16)
            + w4 * __uint_as_float(v4 << 16) + w5 * __uint_as_float(v5 << 16)
            + w6 * __uint_as_float(v6 << 16) + w7 * __uint_as_float(v7 << 16);
        ay += w0 * __uint_as_float(v0 & 0xffff0000u) + w1 * __uint_as_float(v1 & 0xffff0000u)
            + w2 * __uint_as_float(v2 & 0xffff0000u) + w3 * __uint_as_float(v3 & 0xffff0000u)
            + w4 * __uint_as_float(v4 & 0xffff0000u) + w5 * __uint_as_float(v5 & 0xffff0000u)
            + w6 * __uint_as_float(v6 & 0xffff0000u) + w7 * __uint_as_float(v7 & 0xffff0000u);
    }
    for (; j < e1; ++j) {
        int4 e = ed[j];
        float w = __int_as_float(e.z);
        unsigned v = xb[e.x * 64 + lane];
        ax += w * __uint_as_float(v << 16);
        ay += w * __uint_as_float(v & 0xffff0000u);
    }
    float inv = invdeg[r];
    float2 o = make_float2(ax * inv, ay * inv);
    if (bias) { o.x += bias[2 * lane]; o.y += bias[2 * lane + 1]; }
    ((float2*)outp)[r * 64 + lane] = o;
}

// ---------------------------------------------------------------------------
// Fused MLP: h2 = relu(LN(h0 @ W1 + b1)) @ W2, output in bf16 (b2 added later).
// 16-row tiles (grid 1024) for ~2x occupancy vs 32-row. Stage A: wave owns 4
// full rows (lane = 4 of 256 cols) -> LN is a wave shuffle-reduce. Stage B via
// a 16 KB LDS tile. Inner loops k-vectorized x4 (ds_read_b128).
__launch_bounds__(256)
__global__ void fused_mlp_kernel(const float* __restrict__ h0, const float* __restrict__ W1,
                                 const float* __restrict__ b1, const float* __restrict__ W2,
                                 const float* __restrict__ ln_g, const float* __restrict__ ln_b,
                                 unsigned short* __restrict__ h2b) {
    __shared__ float sA[16][F_IN];    // 8 KB
    __shared__ float sH[16][F_HID];   // 16 KB
    int t = threadIdx.x;
    int rbase = blockIdx.x * 16;
    for (int it = 0; it < 2; ++it) {
        int id = t + it * 256;        // [0,512) float4 ids
        int m = id >> 5;
        int k0 = (id & 31) * 4;       // consecutive lanes -> consecutive k: coalesced
        *(float4*)&sA[m][k0] = *(const float4*)&h0[(size_t)(rbase + m) * F_IN + k0];
    }
    __syncthreads();

    int lane = t & 63;
    int c0 = lane * 4;                // 256 cols across the wave
    int m0 = (t >> 6) * 4;            // 4 rows per wave
    float acc[4][4] = {};
    for (int k = 0; k < F_IN; k += 4) {
        float4 a[4];
#pragma unroll
        for (int i = 0; i < 4; ++i) a[i] = *(const float4*)&sA[m0 + i][k];  // broadcast b128
        float4 wk0 = *(const float4*)&W1[(size_t)k       * F_HID + c0];
        float4 wk1 = *(const float4*)&W1[(size_t)(k + 1) * F_HID + c0];
        float4 wk2 = *(const float4*)&W1[(size_t)(k + 2) * F_HID + c0];
        float4 wk3 = *(const float4*)&W1[(size_t)(k + 3) * F_HID + c0];
#pragma unroll
        for (int i = 0; i < 4; ++i) {
            acc[i][0] += a[i].x * wk0.x + a[i].y * wk1.x + a[i].z * wk2.x + a[i].w * wk3.x;
            acc[i][1] += a[i].x * wk0.y + a[i].y * wk1.y + a[i].z * wk2.y + a[i].w * wk3.y;
            acc[i][2] += a[i].x * wk0.z + a[i].y * wk1.z + a[i].z * wk2.z + a[i].w * wk3.z;
            acc[i][3] += a[i].x * wk0.w + a[i].y * wk1.w + a[i].z * wk2.w + a[i].w * wk3.w;
        }
    }
    float4 bias = *(const float4*)&b1[c0];
    float4 g4 = *(const float4*)&ln_g[c0];
    float4 bb4 = *(const float4*)&ln_b[c0];
#pragma unroll
    for (int i = 0; i < 4; ++i) {
        float v0 = acc[i][0] + bias.x, v1 = acc[i][1] + bias.y;
        float v2 = acc[i][2] + bias.z, v3 = acc[i][3] + bias.w;
        float s = v0 + v1 + v2 + v3;
        float q = v0 * v0 + v1 * v1 + v2 * v2 + v3 * v3;
        for (int off = 32; off; off >>= 1) {
            s += __shfl_xor(s, off, 64);
            q += __shfl_xor(q, off, 64);
        }
        float mean = s * (1.0f / F_HID);
        float var = q * (1.0f / F_HID) - mean * mean;
        float rinv = rsqrtf(var + LN_EPS);
        v0 = fmaxf((v0 - mean) * rinv * g4.x + bb4.x, 0.0f);
        v1 = fmaxf((v1 - mean) * rinv * g4.y + bb4.y, 0.0f);
        v2 = fmaxf((v2 - mean) * rinv * g4.z + bb4.z, 0.0f);
        v3 = fmaxf((v3 - mean) * rinv * g4.w + bb4.w, 0.0f);
        *(float4*)&sH[m0 + i][c0] = make_float4(v0, v1, v2, v3);
    }
    __syncthreads();

    // Stage B: [16,256] @ [256,128] -> bf16
    int c0b = (t & 31) * 4;           // 128 cols across half-wave
    int m0b = (t >> 5) * 2;           // 2 rows per half-wave
    float acc2[2][4] = {};
    for (int k = 0; k < F_HID; k += 4) {
        float4 a[2];
#pragma unroll
        for (int i = 0; i < 2; ++i) a[i] = *(const float4*)&sH[m0b + i][k];  // 2-addr b128
        float4 wk0 = *(const float4*)&W2[(size_t)k       * F_OUT + c0b];
        float4 wk1 = *(const float4*)&W2[(size_t)(k + 1) * F_OUT + c0b];
        float4 wk2 = *(const float4*)&W2[(size_t)(k + 2) * F_OUT + c0b];
        float4 wk3 = *(const float4*)&W2[(size_t)(k + 3) * F_OUT + c0b];
#pragma unroll
        for (int i = 0; i < 2; ++i) {
            acc2[i][0] += a[i].x * wk0.x + a[i].y * wk1.x + a[i].z * wk2.x + a[i].w * wk3.x;
            acc2[i][1] += a[i].x * wk0.y + a[i].y * wk1.y + a[i].z * wk2.y + a[i].w * wk3.y;
            acc2[i][2] += a[i].x * wk0.z + a[i].y * wk1.z + a[i].z * wk2.z + a[i].w * wk3.z;
            acc2[i][3] += a[i].x * wk0.w + a[i].y * wk1.w + a[i].z * wk2.w + a[i].w * wk3.w;
        }
    }
#pragma unroll
    for (int i = 0; i < 2; ++i) {
        ushort4 o;
        o.x = bf16rne(acc2[i][0]); o.y = bf16rne(acc2[i][1]);
        o.z = bf16rne(acc2[i][2]); o.w = bf16rne(acc2[i][3]);
        *(ushort4*)&h2b[(size_t)(rbase + m0b + i) * F_OUT + c0b] = o;
    }
}

// ---------------------------------------------------------------------------
extern "C" void kernel_launch(void* const* d_in, const int* in_sizes, int n_in,
                              void* d_out, int out_size, void* d_ws, size_t ws_size,
                              hipStream_t stream) {
    const float* x   = (const float*)d_in[0];
    const void*  ei  = d_in[1];
    const float* ew  = (const float*)d_in[2];
    const float* W1  = (const float*)d_in[3];
    const float* b1  = (const float*)d_in[4];
    const float* W2  = (const float*)d_in[5];
    const float* b2  = (const float*)d_in[6];
    const float* lng = (const float*)d_in[7];
    const float* lnb = (const float*)d_in[8];
    float* out = (float*)d_out;
    int E = in_sizes[2];

    char* w = (char*)d_ws;
    size_t off = 0;
    auto take = [&](size_t bytes) -> char* {
        char* p = w + off;
        off += (bytes + 255) & ~(size_t)255;
        return p;
    };
    int*   rp     = (int*)take((size_t)(N_NODES + 1) * 4);
    int*   cnt    = (int*)take((size_t)N_NODES * 4);
    float* invdeg = (float*)take((size_t)N_NODES * 4);
    int4*  edges  = (int4*)take((size_t)E * 16);
    unsigned short* xb  = (unsigned short*)take((size_t)N_NODES * F_IN * 2);
    unsigned short* h2b = (unsigned short*)take((size_t)N_NODES * F_OUT * 2);
    float* h0     = (float*)take((size_t)N_NODES * F_IN * 4);
    int*   mode   = (int*)take(4);

    detect_mode_kernel<<<1, 256, 0, stream>>>((const unsigned*)ei, mode);
    init_kernel<<<N_NODES / 256, 256, 0, stream>>>(cnt);
    convert_kernel<<<N_NODES * F_IN / 1024, 256, 0, stream>>>(x, xb);
    count_kernel<<<(E + 255) / 256, 256, 0, stream>>>(ei, mode, cnt, E);
    scan_kernel<<<1, 256, 0, stream>>>(cnt, rp);
    fill_kernel<<<(E + 255) / 256, 256, 0, stream>>>(ei, mode, ew, rp, cnt, edges, E);
    dedupe_kernel<<<N_NODES / 4, 256, 0, stream>>>(rp, edges, invdeg);
    // h0 = D^-1 (A+I) x          (x in bf16, acc fp32)
    spmm_bf16_kernel<<<N_NODES / 4, 256, 0, stream>>>((const unsigned*)xb, rp, edges, invdeg, nullptr, h0);
    // h2 = relu(LN(h0 W1 + b1)) W2   (bf16 out)
    fused_mlp_kernel<<<N_NODES / 16, 256, 0, stream>>>(h0, W1, b1, W2, lng, lnb, h2b);
    // out = D^-1 (A+I) h2 + b2   (== (D^-1 (A+I) h) W2 + b2 by linearity)
    spmm_bf16_kernel<<<N_NODES / 4, 256, 0, stream>>>((const unsigned*)h2b, rp, edges, invdeg, b2, out);
}

// Round 5
// 279.232 us; speedup vs baseline: 1.6726x; 1.0399x over previous
//
#include <hip/hip_runtime.h>

#define N_NODES 16384
#define F_IN    128
#define F_HID   256
#define F_OUT   128
#define LN_EPS  1e-5f
#define MAXD    192   // per-row dedupe capacity; P(row deg > 192) ~ 0 for Poisson(32)
#define HSTR    264   // LDS H-row stride in ushorts (256 + 8 pad -> 2-way banks max)

typedef __attribute__((ext_vector_type(8))) short bf16x8;
typedef __attribute__((ext_vector_type(4))) float f32x4;

__device__ __forceinline__ unsigned short bf16rne(float f) {
    unsigned u = __float_as_uint(f);
    unsigned r = (u + 0x7fffu + ((u >> 16) & 1u)) >> 16;   // round-to-nearest-even
    return (unsigned short)r;
}

// ---------------------------------------------------------------------------
// Detect whether edge_index arrived as int64 (odd u32 words all zero) or int32.
__global__ void detect_mode_kernel(const unsigned* ei, int* mode) {
    __shared__ int nz;
    if (threadIdx.x == 0) nz = 0;
    __syncthreads();
    for (int it = 0; it < 4; ++it) {
        int idx = 2 * (threadIdx.x + it * 256) + 1;
        if (ei[idx] != 0u) nz = 1;   // benign race, all writers store 1
    }
    __syncthreads();
    if (threadIdx.x == 0) *mode = (nz == 0) ? 1 : 0;  // 1 => int64
}

// ---------------------------------------------------------------------------
__global__ void init_kernel(int* cnt) {
    int i = blockIdx.x * 256 + threadIdx.x;
    cnt[i] = 0;
}

// ---------------------------------------------------------------------------
// x (fp32) -> bf16, 4 elems/thread.
__global__ void convert_kernel(const float* __restrict__ x, unsigned short* __restrict__ xb) {
    int i = (blockIdx.x * 256 + threadIdx.x) * 4;
    float4 v = *(const float4*)&x[i];
    ushort4 o;
    o.x = bf16rne(v.x); o.y = bf16rne(v.y); o.z = bf16rne(v.z); o.w = bf16rne(v.w);
    *(ushort4*)&xb[i] = o;
}

// ---------------------------------------------------------------------------
// W1 [128k x 256n] fp32 -> W1t [256n x 128k] bf16 (B-operand friendly).
__global__ void prep_w1_kernel(const float* __restrict__ W1, unsigned short* __restrict__ W1t) {
    int id = blockIdx.x * 256 + threadIdx.x;   // 32768
    int n = id >> 7, k = id & 127;
    W1t[id] = bf16rne(W1[(size_t)k * F_HID + n]);
}
// W2 [256k x 128n] fp32 -> W2t [128n x 256k] bf16.
__global__ void prep_w2_kernel(const float* __restrict__ W2, unsigned short* __restrict__ W2t) {
    int id = blockIdx.x * 256 + threadIdx.x;   // 32768
    int n = id >> 8, k = id & 255;
    W2t[id] = bf16rne(W2[(size_t)k * F_OUT + n]);
}

// ---------------------------------------------------------------------------
__global__ void count_kernel(const void* ei, const int* mode, int* cnt, int E) {
    int e = blockIdx.x * 256 + threadIdx.x;
    if (e >= E) return;
    int r = (*mode) ? (int)((const long long*)ei)[e] : ((const int*)ei)[e];
    atomicAdd(&cnt[r], 1);
}

// ---------------------------------------------------------------------------
// Exclusive scan over 16384 row counts; single block. Zeroes cnt for reuse.
__global__ void scan_kernel(int* cnt, int* rp) {
    __shared__ int part[256];
    int t = threadIdx.x;
    int base = t * 64;
    int s = 0;
    for (int i = 0; i < 64; ++i) s += cnt[base + i];
    part[t] = s;
    __syncthreads();
    for (int off = 1; off < 256; off <<= 1) {
        int v = (t >= off) ? part[t - off] : 0;
        __syncthreads();
        part[t] += v;
        __syncthreads();
    }
    int run = (t == 0) ? 0 : part[t - 1];
    for (int i = 0; i < 64; ++i) {
        rp[base + i] = run;
        run += cnt[base + i];
        cnt[base + i] = 0;
    }
    if (t == 255) rp[N_NODES] = run;
}

// ---------------------------------------------------------------------------
// CSR fill with packed entries: edges[pos] = {col, edge_id, w_bits, 0}.
__global__ void fill_kernel(const void* ei, const int* mode, const float* ew,
                            const int* rp, int* cur, int4* edges, int E) {
    int e = blockIdx.x * 256 + threadIdx.x;
    if (e >= E) return;
    int r, c;
    if (*mode) {
        const long long* p = (const long long*)ei;
        r = (int)p[e]; c = (int)p[e + E];
    } else {
        const int* p = (const int*)ei;
        r = p[e]; c = p[e + E];
    }
    int pos = rp[r] + atomicAdd(&cur[r], 1);
    edges[pos] = make_int4(c, e, __float_as_int(ew[e]), 0);
}

// ---------------------------------------------------------------------------
// Per-row dedupe (last edge wins) + degree. One wave per row.
__global__ void dedupe_kernel(const int* __restrict__ rp, int4* __restrict__ edges,
                              float* __restrict__ invdeg) {
    __shared__ int scol[4][MAXD];
    __shared__ int seid[4][MAXD];
    int wave = threadIdx.x >> 6, lane = threadIdx.x & 63;
    int r = blockIdx.x * 4 + wave;
    int j0 = rp[r], j1 = rp[r + 1];
    int d = j1 - j0;
    if (d > MAXD) d = MAXD;
    int   mycol[3], myeid[3];
    float myw[3];
    int nown = 0;
    for (int i = lane; i < d; i += 64) {
        int4 e = edges[j0 + i];
        scol[wave][i] = e.x;
        seid[wave][i] = e.y;
        mycol[nown] = e.x; myeid[nown] = e.y; myw[nown] = __int_as_float(e.z);
        ++nown;
    }
    __syncthreads();
    float wsum = 0.0f;
    nown = 0;
    for (int i = lane; i < d; i += 64) {
        bool kill = false;
        for (int j = 0; j < d; ++j)
            if (scol[wave][j] == mycol[nown] && seid[wave][j] > myeid[nown]) { kill = true; break; }
        if (kill) ((int*)&edges[j0 + i])[2] = 0;   // zero the weight
        else wsum += myw[nown];
        ++nown;
    }
    for (int off = 32; off; off >>= 1) wsum += __shfl_xor(wsum, off, 64);
    if (lane == 0) invdeg[r] = 1.0f / (1.0f + wsum);   // +1 self-loop; >=1 so clip no-op
}

// ---------------------------------------------------------------------------
// Gather SpMM over 128 bf16 feature cols: one wave per row, 1 uint (2 bf16)/lane.
// x8 unroll keeps 8 gathers in flight. fp32 accumulate. Output fp32 (+bias) or bf16.
__global__ void spmm_bf16_kernel(const unsigned* __restrict__ xb, const int* __restrict__ rp,
                                 const int4* __restrict__ ed, const float* __restrict__ invdeg,
                                 const float* __restrict__ bias, void* __restrict__ outp,
                                 int out_bf16) {
    int wave = threadIdx.x >> 6, lane = threadIdx.x & 63;
    int r = blockIdx.x * 4 + wave;
    unsigned self = xb[r * 64 + lane];
    float ax = __uint_as_float(self << 16);
    float ay = __uint_as_float(self & 0xffff0000u);
    int j = rp[r], e1 = rp[r + 1];
    for (; j + 8 <= e1; j += 8) {
        int4 e0 = ed[j],     e1q = ed[j + 1], e2 = ed[j + 2], e3 = ed[j + 3];
        int4 e4 = ed[j + 4], e5  = ed[j + 5], e6 = ed[j + 6], e7 = ed[j + 7];
        unsigned v0 = xb[e0.x * 64 + lane];
        unsigned v1 = xb[e1q.x * 64 + lane];
        unsigned v2 = xb[e2.x * 64 + lane];
        unsigned v3 = xb[e3.x * 64 + lane];
        unsigned v4 = xb[e4.x * 64 + lane];
        unsigned v5 = xb[e5.x * 64 + lane];
        unsigned v6 = xb[e6.x * 64 + lane];
        unsigned v7 = xb[e7.x * 64 + lane];
        float w0 = __int_as_float(e0.z), w1 = __int_as_float(e1q.z);
        float w2 = __int_as_float(e2.z), w3 = __int_as_float(e3.z);
        float w4 = __int_as_float(e4.z), w5 = __int_as_float(e5.z);
        float w6 = __int_as_float(e6.z), w7 = __int_as_float(e7.z);
        ax += w0 * __uint_as_float(v0 << 16) + w1 * __uint_as_float(v1 << 16)
            + w2 * __uint_as_float(v2 << 16) + w3 * __uint_as_float(v3 << 16)
            + w4 * __uint_as_float(v4 << 16) + w5 * __uint_as_float(v5 << 16)
            + w6 * __uint_as_float(v6 << 16) + w7 * __uint_as_float(v7 << 16);
        ay += w0 * __uint_as_float(v0 & 0xffff0000u) + w1 * __uint_as_float(v1 & 0xffff0000u)
            + w2 * __uint_as_float(v2 & 0xffff0000u) + w3 * __uint_as_float(v3 & 0xffff0000u)
            + w4 * __uint_as_float(v4 & 0xffff0000u) + w5 * __uint_as_float(v5 & 0xffff0000u)
            + w6 * __uint_as_float(v6 & 0xffff0000u) + w7 * __uint_as_float(v7 & 0xffff0000u);
    }
    for (; j < e1; ++j) {
        int4 e = ed[j];
        float w = __int_as_float(e.z);
        unsigned v = xb[e.x * 64 + lane];
        ax += w * __uint_as_float(v << 16);
        ay += w * __uint_as_float(v & 0xffff0000u);
    }
    float inv = invdeg[r];
    float ox = ax * inv, oy = ay * inv;
    if (bias) { ox += bias[2 * lane]; oy += bias[2 * lane + 1]; }
    if (out_bf16) {
        unsigned pk = ((unsigned)bf16rne(oy) << 16) | (unsigned)bf16rne(ox);
        ((unsigned*)outp)[r * 64 + lane] = pk;
    } else {
        ((float2*)outp)[r * 64 + lane] = make_float2(ox, oy);
    }
}

// ---------------------------------------------------------------------------
// MFMA MLP: h2 = relu(LN(h0 @ W1 + b1)) @ W2  in bf16 (b2 added in spmm2).
// One wave owns 16 rows end-to-end; 4 waves/block (64 rows), grid 256.
// mfma_f32_16x16x32_bf16: C/D col=lane&15 row=quad*4+reg; A[m=lane&15][k=quad*8+j].
// W1t/W2t are [n][k] bf16 so B-frags are contiguous 16B loads (L1/L2-resident).
__launch_bounds__(256)
__global__ void mlp_mfma_kernel(const unsigned short* __restrict__ h0b,
                                const unsigned short* __restrict__ W1t,
                                const unsigned short* __restrict__ W2t,
                                const float* __restrict__ b1,
                                const float* __restrict__ ln_g, const float* __restrict__ ln_b,
                                unsigned short* __restrict__ h2b) {
    __shared__ unsigned short Hs[4][16 * HSTR];    // ~33 KB
    int t = threadIdx.x;
    int wid = t >> 6, lane = t & 63;
    int lnid = lane & 15, quad = lane >> 4;
    int R = blockIdx.x * 64 + wid * 16;
    unsigned short* H = Hs[wid];

    // ---- stage A: C1[16x256] = h0[R.., 128] @ W1, K=128 ----
    bf16x8 a[4];
#pragma unroll
    for (int ch = 0; ch < 4; ++ch)
        a[ch] = *(const bf16x8*)&h0b[(size_t)(R + lnid) * F_IN + ch * 32 + quad * 8];
    f32x4 acc[16];
#pragma unroll
    for (int ct = 0; ct < 16; ++ct) {
        f32x4 c = {0.0f, 0.0f, 0.0f, 0.0f};
        const unsigned short* wrow = &W1t[(size_t)(ct * 16 + lnid) * F_IN];
#pragma unroll
        for (int ch = 0; ch < 4; ++ch) {
            bf16x8 b = *(const bf16x8*)&wrow[ch * 32 + quad * 8];
            c = __builtin_amdgcn_mfma_f32_16x16x32_bf16(a[ch], b, c, 0, 0, 0);
        }
        acc[ct] = c;
    }
    // bias + LN stats (rows live in (quad,reg); cols in (ct,lnid))
    float s[4] = {0, 0, 0, 0}, q[4] = {0, 0, 0, 0};
#pragma unroll
    for (int ct = 0; ct < 16; ++ct) {
        float bv = b1[ct * 16 + lnid];
#pragma unroll
        for (int r = 0; r < 4; ++r) {
            float v = acc[ct][r] + bv;
            acc[ct][r] = v;
            s[r] += v; q[r] += v * v;
        }
    }
#pragma unroll
    for (int r = 0; r < 4; ++r)
        for (int off = 1; off < 16; off <<= 1) {
            s[r] += __shfl_xor(s[r], off, 64);
            q[r] += __shfl_xor(q[r], off, 64);
        }
    float mean[4], rinv[4];
#pragma unroll
    for (int r = 0; r < 4; ++r) {
        mean[r] = s[r] * (1.0f / F_HID);
        float var = q[r] * (1.0f / F_HID) - mean[r] * mean[r];
        rinv[r] = rsqrtf(var + LN_EPS);
    }
#pragma unroll
    for (int ct = 0; ct < 16; ++ct) {
        int c = ct * 16 + lnid;
        float g = ln_g[c], bb = ln_b[c];
#pragma unroll
        for (int r = 0; r < 4; ++r) {
            float v = fmaxf((acc[ct][r] - mean[r]) * rinv[r] * g + bb, 0.0f);
            H[(quad * 4 + r) * HSTR + c] = bf16rne(v);
        }
    }
    __syncthreads();   // drain LDS writes before A-layout reads

    // ---- stage B: C2[16x128] = H[16x256] @ W2, K=256 ----
    bf16x8 a2[8];
#pragma unroll
    for (int ch = 0; ch < 8; ++ch)
        a2[ch] = *(const bf16x8*)&H[lnid * HSTR + ch * 32 + quad * 8];
#pragma unroll
    for (int ct = 0; ct < 8; ++ct) {
        f32x4 c = {0.0f, 0.0f, 0.0f, 0.0f};
        const unsigned short* wrow = &W2t[(size_t)(ct * 16 + lnid) * F_HID];
#pragma unroll
        for (int ch = 0; ch < 8; ++ch) {
            bf16x8 b = *(const bf16x8*)&wrow[ch * 32 + quad * 8];
            c = __builtin_amdgcn_mfma_f32_16x16x32_bf16(a2[ch], b, c, 0, 0, 0);
        }
        // C2 -> LDS repack area (stride 132 ushorts; a2 regs already hold all H)
#pragma unroll
        for (int r = 0; r < 4; ++r)
            H[(quad * 4 + r) * 132 + ct * 16 + lnid] = bf16rne(c[r]);
    }
    __syncthreads();   // drain before coalesced readback

    // coalesced store: 16 rows x 128 bf16
#pragma unroll
    for (int p = 0; p < 8; ++p) {
        int flat = p * 64 + lane;           // ushort4 id in [0,512)
        int m = flat >> 5, cg = flat & 31;
        *(ushort4*)&h2b[(size_t)(R + m) * F_OUT + cg * 4] =
            *(const ushort4*)&H[m * 132 + cg * 4];
    }
}

// ---------------------------------------------------------------------------
extern "C" void kernel_launch(void* const* d_in, const int* in_sizes, int n_in,
                              void* d_out, int out_size, void* d_ws, size_t ws_size,
                              hipStream_t stream) {
    const float* x   = (const float*)d_in[0];
    const void*  ei  = d_in[1];
    const float* ew  = (const float*)d_in[2];
    const float* W1  = (const float*)d_in[3];
    const float* b1  = (const float*)d_in[4];
    const float* W2  = (const float*)d_in[5];
    const float* b2  = (const float*)d_in[6];
    const float* lng = (const float*)d_in[7];
    const float* lnb = (const float*)d_in[8];
    float* out = (float*)d_out;
    int E = in_sizes[2];

    char* w = (char*)d_ws;
    size_t off = 0;
    auto take = [&](size_t bytes) -> char* {
        char* p = w + off;
        off += (bytes + 255) & ~(size_t)255;
        return p;
    };
    int*   rp     = (int*)take((size_t)(N_NODES + 1) * 4);
    int*   cnt    = (int*)take((size_t)N_NODES * 4);
    float* invdeg = (float*)take((size_t)N_NODES * 4);
    int4*  edges  = (int4*)take((size_t)E * 16);
    unsigned short* xb  = (unsigned short*)take((size_t)N_NODES * F_IN * 2);
    unsigned short* h0b = (unsigned short*)take((size_t)N_NODES * F_IN * 2);
    unsigned short* h2b = (unsigned short*)take((size_t)N_NODES * F_OUT * 2);
    unsigned short* W1t = (unsigned short*)take((size_t)F_IN * F_HID * 2);
    unsigned short* W2t = (unsigned short*)take((size_t)F_HID * F_OUT * 2);
    int*   mode   = (int*)take(4);

    detect_mode_kernel<<<1, 256, 0, stream>>>((const unsigned*)ei, mode);
    init_kernel<<<N_NODES / 256, 256, 0, stream>>>(cnt);
    convert_kernel<<<N_NODES * F_IN / 1024, 256, 0, stream>>>(x, xb);
    prep_w1_kernel<<<F_IN * F_HID / 256, 256, 0, stream>>>(W1, W1t);
    prep_w2_kernel<<<F_HID * F_OUT / 256, 256, 0, stream>>>(W2, W2t);
    count_kernel<<<(E + 255) / 256, 256, 0, stream>>>(ei, mode, cnt, E);
    scan_kernel<<<1, 256, 0, stream>>>(cnt, rp);
    fill_kernel<<<(E + 255) / 256, 256, 0, stream>>>(ei, mode, ew, rp, cnt, edges, E);
    dedupe_kernel<<<N_NODES / 4, 256, 0, stream>>>(rp, edges, invdeg);
    // h0b = bf16( D^-1 (A+I) x )
    spmm_bf16_kernel<<<N_NODES / 4, 256, 0, stream>>>((const unsigned*)xb, rp, edges, invdeg,
                                                      nullptr, h0b, 1);
    // h2b = bf16( relu(LN(h0 W1 + b1)) W2 )
    mlp_mfma_kernel<<<N_NODES / 64, 256, 0, stream>>>(h0b, W1t, W2t, b1, lng, lnb, h2b);
    // out = D^-1 (A+I) h2 + b2   (== (D^-1 (A+I) h) W2 + b2 by linearity)
    spmm_bf16_kernel<<<N_NODES / 4, 256, 0, stream>>>((const unsigned*)h2b, rp, edges, invdeg,
                                                      b2, out, 0);
}

// Round 6
// 201.462 us; speedup vs baseline: 2.3182x; 1.3860x over previous
//
#include <hip/hip_runtime.h>

#define N_NODES 16384
#define F_IN    128
#define F_HID   256
#define F_OUT   128
#define LN_EPS  1e-5f
#define CAP     128   // ELL slots/row; P(deg>128) ~ 1e-20 for Poisson(32)
#define HSTR    264   // LDS H-row stride in ushorts (256 + 8 pad -> 2-way banks max)

typedef __attribute__((ext_vector_type(8))) short bf16x8;
typedef __attribute__((ext_vector_type(4))) float f32x4;

__device__ __forceinline__ unsigned short bf16rne(float f) {
    unsigned u = __float_as_uint(f);
    unsigned r = (u + 0x7fffu + ((u >> 16) & 1u)) >> 16;   // round-to-nearest-even
    return (unsigned short)r;
}

// ---------------------------------------------------------------------------
// Prelude (one launch): blockIdx ranges do independent prep work.
//  [0,2048)    : x fp32 -> bf16
//  [2048,2176) : W1 [128k x 256n] -> W1t [256n x 128k] bf16
//  [2176,2304) : W2 [256k x 128n] -> W2t [128n x 256k] bf16
//  [2304,2368) : cur[] = 0
//  2368        : detect int64 vs int32 edge_index (odd u32 words all zero)
__global__ void prelude_kernel(const float* __restrict__ x, unsigned short* __restrict__ xb,
                               const float* __restrict__ W1, unsigned short* __restrict__ W1t,
                               const float* __restrict__ W2, unsigned short* __restrict__ W2t,
                               int* __restrict__ cur, const unsigned* __restrict__ ei,
                               int* __restrict__ mode) {
    int b = blockIdx.x, t = threadIdx.x;
    if (b < 2048) {
        int i = (b * 256 + t) * 4;
        float4 v = *(const float4*)&x[i];
        ushort4 o;
        o.x = bf16rne(v.x); o.y = bf16rne(v.y); o.z = bf16rne(v.z); o.w = bf16rne(v.w);
        *(ushort4*)&xb[i] = o;
    } else if (b < 2176) {
        int id = (b - 2048) * 256 + t;        // [0, 32768)
        int n = id >> 7, k = id & 127;
        W1t[id] = bf16rne(W1[(size_t)k * F_HID + n]);
    } else if (b < 2304) {
        int id = (b - 2176) * 256 + t;        // [0, 32768)
        int n = id >> 8, k = id & 255;
        W2t[id] = bf16rne(W2[(size_t)k * F_OUT + n]);
    } else if (b < 2368) {
        cur[(b - 2304) * 256 + t] = 0;
    } else {
        __shared__ int nz;
        if (t == 0) nz = 0;
        __syncthreads();
        for (int it = 0; it < 4; ++it) {
            int idx = 2 * (t + it * 256) + 1;
            if (ei[idx] != 0u) nz = 1;        // benign race
        }
        __syncthreads();
        if (t == 0) *mode = (nz == 0) ? 1 : 0;  // 1 => int64
    }
}

// ---------------------------------------------------------------------------
// ELL fill: 4 independent edges/thread -> 4 overlapping atomic chains.
// Entry = int2{col, edge_id}; dedupe later replaces .y with weight bits.
__global__ void fill_kernel(const void* __restrict__ ei, const int* __restrict__ mode,
                            int* __restrict__ cur, int2* __restrict__ ed, int E) {
    int base = blockIdx.x * 1024 + threadIdx.x;
    int m = *mode;
#pragma unroll
    for (int u = 0; u < 4; ++u) {
        int e = base + u * 256;
        if (e >= E) continue;
        int r, c;
        if (m) {
            const long long* p = (const long long*)ei;
            r = (int)p[e]; c = (int)p[e + E];
        } else {
            const int* p = (const int*)ei;
            r = p[e]; c = p[e + E];
        }
        int pos = atomicAdd(&cur[r], 1);
        if (pos < CAP) ed[r * CAP + pos] = make_int2(c, e);
    }
}

// ---------------------------------------------------------------------------
// Per-row dedupe (last edge_id wins) + degree. One wave per row. Rewrites each
// entry's .y from edge_id to weight bits (0 if superseded); invdeg = 1/(1+sum).
__global__ void dedupe_kernel(const float* __restrict__ ew, int* __restrict__ cur,
                              int2* __restrict__ ed, float* __restrict__ invdeg) {
    __shared__ int scol[4][CAP];
    __shared__ int seid[4][CAP];
    int wave = threadIdx.x >> 6, lane = threadIdx.x & 63;
    int r = blockIdx.x * 4 + wave;
    int d = cur[r];
    if (d > CAP) d = CAP;
    int2* row = ed + r * CAP;
    int mycol[2], myeid[2];
    int nown = 0;
    for (int i = lane; i < d; i += 64) {
        int2 e = row[i];
        scol[wave][i] = e.x;
        seid[wave][i] = e.y;
        mycol[nown] = e.x; myeid[nown] = e.y;
        ++nown;
    }
    __syncthreads();
    float wsum = 0.0f;
    nown = 0;
    for (int i = lane; i < d; i += 64) {
        bool kill = false;
        for (int j = 0; j < d; ++j)
            if (scol[wave][j] == mycol[nown] && seid[wave][j] > myeid[nown]) { kill = true; break; }
        float w = kill ? 0.0f : ew[myeid[nown]];
        ((int*)&row[i])[1] = __float_as_int(w);   // .y: edge_id -> weight
        wsum += w;
        ++nown;
    }
    for (int off = 32; off; off >>= 1) wsum += __shfl_xor(wsum, off, 64);
    if (lane == 0) {
        invdeg[r] = 1.0f / (1.0f + wsum);   // +1 self-loop; >=1 so clip no-op
        cur[r] = d;                          // clamped degree for spmm
    }
}

// ---------------------------------------------------------------------------
// Gather SpMM over 128 bf16 feature cols (ELL): one wave per row, 1 uint
// (2 bf16)/lane. x8 unroll keeps 8 gathers in flight. fp32 accumulate.
// Output fp32 (+bias) or packed bf16.
__global__ void spmm_bf16_kernel(const unsigned* __restrict__ xb, const int* __restrict__ cur,
                                 const int2* __restrict__ ed, const float* __restrict__ invdeg,
                                 const float* __restrict__ bias, void* __restrict__ outp,
                                 int out_bf16) {
    int wave = threadIdx.x >> 6, lane = threadIdx.x & 63;
    int r = blockIdx.x * 4 + wave;
    const int2* row = ed + r * CAP;
    int d = cur[r];
    unsigned self = xb[r * 64 + lane];
    float ax = __uint_as_float(self << 16);
    float ay = __uint_as_float(self & 0xffff0000u);
    int j = 0;
    for (; j + 8 <= d; j += 8) {
        int2 e0 = row[j],     e1 = row[j + 1], e2 = row[j + 2], e3 = row[j + 3];
        int2 e4 = row[j + 4], e5 = row[j + 5], e6 = row[j + 6], e7 = row[j + 7];
        unsigned v0 = xb[e0.x * 64 + lane];
        unsigned v1 = xb[e1.x * 64 + lane];
        unsigned v2 = xb[e2.x * 64 + lane];
        unsigned v3 = xb[e3.x * 64 + lane];
        unsigned v4 = xb[e4.x * 64 + lane];
        unsigned v5 = xb[e5.x * 64 + lane];
        unsigned v6 = xb[e6.x * 64 + lane];
        unsigned v7 = xb[e7.x * 64 + lane];
        float w0 = __int_as_float(e0.y), w1 = __int_as_float(e1.y);
        float w2 = __int_as_float(e2.y), w3 = __int_as_float(e3.y);
        float w4 = __int_as_float(e4.y), w5 = __int_as_float(e5.y);
        float w6 = __int_as_float(e6.y), w7 = __int_as_float(e7.y);
        ax += w0 * __uint_as_float(v0 << 16) + w1 * __uint_as_float(v1 << 16)
            + w2 * __uint_as_float(v2 << 16) + w3 * __uint_as_float(v3 << 16)
            + w4 * __uint_as_float(v4 << 16) + w5 * __uint_as_float(v5 << 16)
            + w6 * __uint_as_float(v6 << 16) + w7 * __uint_as_float(v7 << 16);
        ay += w0 * __uint_as_float(v0 & 0xffff0000u) + w1 * __uint_as_float(v1 & 0xffff0000u)
            + w2 * __uint_as_float(v2 & 0xffff0000u) + w3 * __uint_as_float(v3 & 0xffff0000u)
            + w4 * __uint_as_float(v4 & 0xffff0000u) + w5 * __uint_as_float(v5 & 0xffff0000u)
            + w6 * __uint_as_float(v6 & 0xffff0000u) + w7 * __uint_as_float(v7 & 0xffff0000u);
    }
    for (; j < d; ++j) {
        int2 e = row[j];
        float w = __int_as_float(e.y);
        unsigned v = xb[e.x * 64 + lane];
        ax += w * __uint_as_float(v << 16);
        ay += w * __uint_as_float(v & 0xffff0000u);
    }
    float inv = invdeg[r];
    float ox = ax * inv, oy = ay * inv;
    if (bias) { ox += bias[2 * lane]; oy += bias[2 * lane + 1]; }
    if (out_bf16) {
        unsigned pk = ((unsigned)bf16rne(oy) << 16) | (unsigned)bf16rne(ox);
        ((unsigned*)outp)[r * 64 + lane] = pk;
    } else {
        ((float2*)outp)[r * 64 + lane] = make_float2(ox, oy);
    }
}

// ---------------------------------------------------------------------------
// MFMA MLP: h2 = relu(LN(h0 @ W1 + b1)) @ W2  in bf16 (b2 added in spmm2).
// One wave owns 16 rows end-to-end; 4 waves/block (64 rows), grid 256.
// mfma_f32_16x16x32_bf16: C/D col=lane&15 row=quad*4+reg; A[m=lane&15][k=quad*8+j].
// W1t/W2t are [n][k] bf16 so B-frags are contiguous 16B loads (L1/L2-resident).
__launch_bounds__(256)
__global__ void mlp_mfma_kernel(const unsigned short* __restrict__ h0b,
                                const unsigned short* __restrict__ W1t,
                                const unsigned short* __restrict__ W2t,
                                const float* __restrict__ b1,
                                const float* __restrict__ ln_g, const float* __restrict__ ln_b,
                                unsigned short* __restrict__ h2b) {
    __shared__ unsigned short Hs[4][16 * HSTR];    // ~33 KB
    int t = threadIdx.x;
    int wid = t >> 6, lane = t & 63;
    int lnid = lane & 15, quad = lane >> 4;
    int R = blockIdx.x * 64 + wid * 16;
    unsigned short* H = Hs[wid];

    // ---- stage A: C1[16x256] = h0[R.., 128] @ W1, K=128 ----
    bf16x8 a[4];
#pragma unroll
    for (int ch = 0; ch < 4; ++ch)
        a[ch] = *(const bf16x8*)&h0b[(size_t)(R + lnid) * F_IN + ch * 32 + quad * 8];
    f32x4 acc[16];
#pragma unroll
    for (int ct = 0; ct < 16; ++ct) {
        f32x4 c = {0.0f, 0.0f, 0.0f, 0.0f};
        const unsigned short* wrow = &W1t[(size_t)(ct * 16 + lnid) * F_IN];
#pragma unroll
        for (int ch = 0; ch < 4; ++ch) {
            bf16x8 b = *(const bf16x8*)&wrow[ch * 32 + quad * 8];
            c = __builtin_amdgcn_mfma_f32_16x16x32_bf16(a[ch], b, c, 0, 0, 0);
        }
        acc[ct] = c;
    }
    // bias + LN stats (rows live in (quad,reg); cols in (ct,lnid))
    float s[4] = {0, 0, 0, 0}, q[4] = {0, 0, 0, 0};
#pragma unroll
    for (int ct = 0; ct < 16; ++ct) {
        float bv = b1[ct * 16 + lnid];
#pragma unroll
        for (int r = 0; r < 4; ++r) {
            float v = acc[ct][r] + bv;
            acc[ct][r] = v;
            s[r] += v; q[r] += v * v;
        }
    }
#pragma unroll
    for (int r = 0; r < 4; ++r)
        for (int off = 1; off < 16; off <<= 1) {
            s[r] += __shfl_xor(s[r], off, 64);
            q[r] += __shfl_xor(q[r], off, 64);
        }
    float mean[4], rinv[4];
#pragma unroll
    for (int r = 0; r < 4; ++r) {
        mean[r] = s[r] * (1.0f / F_HID);
        float var = q[r] * (1.0f / F_HID) - mean[r] * mean[r];
        rinv[r] = rsqrtf(var + LN_EPS);
    }
#pragma unroll
    for (int ct = 0; ct < 16; ++ct) {
        int c = ct * 16 + lnid;
        float g = ln_g[c], bb = ln_b[c];
#pragma unroll
        for (int r = 0; r < 4; ++r) {
            float v = fmaxf((acc[ct][r] - mean[r]) * rinv[r] * g + bb, 0.0f);
            H[(quad * 4 + r) * HSTR + c] = bf16rne(v);
        }
    }
    __syncthreads();   // drain LDS writes before A-layout reads

    // ---- stage B: C2[16x128] = H[16x256] @ W2, K=256 ----
    bf16x8 a2[8];
#pragma unroll
    for (int ch = 0; ch < 8; ++ch)
        a2[ch] = *(const bf16x8*)&H[lnid * HSTR + ch * 32 + quad * 8];
#pragma unroll
    for (int ct = 0; ct < 8; ++ct) {
        f32x4 c = {0.0f, 0.0f, 0.0f, 0.0f};
        const unsigned short* wrow = &W2t[(size_t)(ct * 16 + lnid) * F_HID];
#pragma unroll
        for (int ch = 0; ch < 8; ++ch) {
            bf16x8 b = *(const bf16x8*)&wrow[ch * 32 + quad * 8];
            c = __builtin_amdgcn_mfma_f32_16x16x32_bf16(a2[ch], b, c, 0, 0, 0);
        }
        // C2 -> LDS repack area (stride 132 ushorts)
#pragma unroll
        for (int r = 0; r < 4; ++r)
            H[(quad * 4 + r) * 132 + ct * 16 + lnid] = bf16rne(c[r]);
    }
    __syncthreads();   // drain before coalesced readback

    // coalesced store: 16 rows x 128 bf16
#pragma unroll
    for (int p = 0; p < 8; ++p) {
        int flat = p * 64 + lane;           // ushort4 id in [0,512)
        int m = flat >> 5, cg = flat & 31;
        *(ushort4*)&h2b[(size_t)(R + m) * F_OUT + cg * 4] =
            *(const ushort4*)&H[m * 132 + cg * 4];
    }
}

// ---------------------------------------------------------------------------
extern "C" void kernel_launch(void* const* d_in, const int* in_sizes, int n_in,
                              void* d_out, int out_size, void* d_ws, size_t ws_size,
                              hipStream_t stream) {
    const float* x   = (const float*)d_in[0];
    const void*  ei  = d_in[1];
    const float* ew  = (const float*)d_in[2];
    const float* W1  = (const float*)d_in[3];
    const float* b1  = (const float*)d_in[4];
    const float* W2  = (const float*)d_in[5];
    const float* b2  = (const float*)d_in[6];
    const float* lng = (const float*)d_in[7];
    const float* lnb = (const float*)d_in[8];
    float* out = (float*)d_out;
    int E = in_sizes[2];

    char* w = (char*)d_ws;
    size_t off = 0;
    auto take = [&](size_t bytes) -> char* {
        char* p = w + off;
        off += (bytes + 255) & ~(size_t)255;
        return p;
    };
    int*   cur    = (int*)take((size_t)N_NODES * 4);
    float* invdeg = (float*)take((size_t)N_NODES * 4);
    int2*  ed     = (int2*)take((size_t)N_NODES * CAP * 8);
    unsigned short* xb  = (unsigned short*)take((size_t)N_NODES * F_IN * 2);
    unsigned short* h0b = (unsigned short*)take((size_t)N_NODES * F_IN * 2);
    unsigned short* h2b = (unsigned short*)take((size_t)N_NODES * F_OUT * 2);
    unsigned short* W1t = (unsigned short*)take((size_t)F_IN * F_HID * 2);
    unsigned short* W2t = (unsigned short*)take((size_t)F_HID * F_OUT * 2);
    int*   mode   = (int*)take(4);

    prelude_kernel<<<2369, 256, 0, stream>>>(x, xb, W1, W1t, W2, W2t, cur,
                                             (const unsigned*)ei, mode);
    fill_kernel<<<(E + 1023) / 1024, 256, 0, stream>>>(ei, mode, cur, ed, E);
    dedupe_kernel<<<N_NODES / 4, 256, 0, stream>>>(ew, cur, ed, invdeg);
    // h0b = bf16( D^-1 (A+I) x )
    spmm_bf16_kernel<<<N_NODES / 4, 256, 0, stream>>>((const unsigned*)xb, cur, ed, invdeg,
                                                      nullptr, h0b, 1);
    // h2b = bf16( relu(LN(h0 W1 + b1)) W2 )
    mlp_mfma_kernel<<<N_NODES / 64, 256, 0, stream>>>(h0b, W1t, W2t, b1, lng, lnb, h2b);
    // out = D^-1 (A+I) h2 + b2   (== (D^-1 (A+I) h) W2 + b2 by linearity)
    spmm_bf16_kernel<<<N_NODES / 4, 256, 0, stream>>>((const unsigned*)h2b, cur, ed, invdeg,
                                                      b2, out, 0);
}

// Round 7
// 191.354 us; speedup vs baseline: 2.4407x; 1.0528x over previous
//
#include <hip/hip_runtime.h>

#define N_NODES 16384
#define F_IN    128
#define F_HID   256
#define F_OUT   128
#define LN_EPS  1e-5f
#define CAP     128   // ELL slots/row; P(deg>128) ~ 1e-20 for Poisson(32)
#define HSTR    264   // LDS H-row stride in ushorts (256 + 8 pad -> 2-way banks max)

typedef __attribute__((ext_vector_type(8))) short bf16x8;
typedef __attribute__((ext_vector_type(4))) float f32x4;

__device__ __forceinline__ unsigned short bf16rne(float f) {
    unsigned u = __float_as_uint(f);
    unsigned r = (u + 0x7fffu + ((u >> 16) & 1u)) >> 16;   // round-to-nearest-even
    return (unsigned short)r;
}
__device__ __forceinline__ float bf_lo(unsigned v) { return __uint_as_float(v << 16); }
__device__ __forceinline__ float bf_hi(unsigned v) { return __uint_as_float(v & 0xffff0000u); }

// ---------------------------------------------------------------------------
// Prelude (one launch): blockIdx ranges do independent prep work.
//  [0,2048)    : x fp32 -> bf16
//  [2048,2176) : W1 [128k x 256n] -> W1t [256n x 128k] bf16
//  [2176,2304) : W2 [256k x 128n] -> W2t [128n x 256k] bf16
//  [2304,2368) : cur[] = 0
//  2368        : detect int64 vs int32 edge_index (odd u32 words all zero)
__global__ void prelude_kernel(const float* __restrict__ x, unsigned short* __restrict__ xb,
                               const float* __restrict__ W1, unsigned short* __restrict__ W1t,
                               const float* __restrict__ W2, unsigned short* __restrict__ W2t,
                               int* __restrict__ cur, const unsigned* __restrict__ ei,
                               int* __restrict__ mode) {
    int b = blockIdx.x, t = threadIdx.x;
    if (b < 2048) {
        int i = (b * 256 + t) * 4;
        float4 v = *(const float4*)&x[i];
        ushort4 o;
        o.x = bf16rne(v.x); o.y = bf16rne(v.y); o.z = bf16rne(v.z); o.w = bf16rne(v.w);
        *(ushort4*)&xb[i] = o;
    } else if (b < 2176) {
        int id = (b - 2048) * 256 + t;        // [0, 32768)
        int n = id >> 7, k = id & 127;
        W1t[id] = bf16rne(W1[(size_t)k * F_HID + n]);
    } else if (b < 2304) {
        int id = (b - 2176) * 256 + t;        // [0, 32768)
        int n = id >> 8, k = id & 255;
        W2t[id] = bf16rne(W2[(size_t)k * F_OUT + n]);
    } else if (b < 2368) {
        cur[(b - 2304) * 256 + t] = 0;
    } else {
        __shared__ int nz;
        if (t == 0) nz = 0;
        __syncthreads();
        for (int it = 0; it < 4; ++it) {
            int idx = 2 * (t + it * 256) + 1;
            if (ei[idx] != 0u) nz = 1;        // benign race
        }
        __syncthreads();
        if (t == 0) *mode = (nz == 0) ? 1 : 0;  // 1 => int64
    }
}

// ---------------------------------------------------------------------------
// ELL fill: 4 independent edges/thread -> 4 overlapping atomic chains.
// Entry = int2{col, edge_id}; dedupe later replaces .y with weight bits.
__global__ void fill_kernel(const void* __restrict__ ei, const int* __restrict__ mode,
                            int* __restrict__ cur, int2* __restrict__ ed, int E) {
    int base = blockIdx.x * 1024 + threadIdx.x;
    int m = *mode;
#pragma unroll
    for (int u = 0; u < 4; ++u) {
        int e = base + u * 256;
        if (e >= E) continue;
        int r, c;
        if (m) {
            const long long* p = (const long long*)ei;
            r = (int)p[e]; c = (int)p[e + E];
        } else {
            const int* p = (const int*)ei;
            r = p[e]; c = p[e + E];
        }
        if (((unsigned)r | (unsigned)c) >= N_NODES) continue;   // replay-safety guard
        int pos = atomicAdd(&cur[r], 1);
        if (pos < CAP) ed[r * CAP + pos] = make_int2(c, e);
    }
}

// ---------------------------------------------------------------------------
// Fused dedupe + SpMM1. One wave per row:
//  1) stage {col, edge_id} in LDS, 2) last-edge-wins dedupe, weight gather from
//  ew, write weights back to ed.y (for spmm2) + invdeg, 3) gather-SpMM from xb
//  using LDS-resident cols/weights, 16 gathers in flight, 4) bf16 h0 out.
__global__ void dd_spmm1_kernel(const float* __restrict__ ew, int* __restrict__ cur,
                                int2* __restrict__ ed, float* __restrict__ invdeg,
                                const unsigned* __restrict__ xb,
                                unsigned* __restrict__ h0b) {
    __shared__ int   scol[4][CAP];
    __shared__ int   seid[4][CAP];
    __shared__ float sw[4][CAP];
    int wave = threadIdx.x >> 6, lane = threadIdx.x & 63;
    int r = blockIdx.x * 4 + wave;
    int d = cur[r];
    if (d > CAP) d = CAP;
    int2* row = ed + r * CAP;

    for (int i = lane; i < d; i += 64) {
        int2 e = row[i];
        scol[wave][i] = e.x;
        seid[wave][i] = e.y;
    }
    __syncthreads();

    float wsum = 0.0f;
    for (int i = lane; i < d; i += 64) {
        int myc = scol[wave][i], mye = seid[wave][i];
        bool kill = false;
        for (int j = 0; j < d; ++j)
            if (scol[wave][j] == myc && seid[wave][j] > mye) { kill = true; break; }
        float w = kill ? 0.0f : ew[mye];
        sw[wave][i] = w;
        ((int*)&row[i])[1] = __float_as_int(w);   // .y: edge_id -> weight (for spmm2)
        wsum += w;
    }
    for (int off = 32; off; off >>= 1) wsum += __shfl_xor(wsum, off, 64);
    float inv = 1.0f / (1.0f + wsum);             // +1 self-loop; >=1 so clip no-op
    if (lane == 0) { invdeg[r] = inv; cur[r] = d; }
    __syncthreads();

    unsigned self = xb[r * 64 + lane];
    float ax = bf_lo(self), ay = bf_hi(self);
    int j = 0;
    for (; j + 16 <= d; j += 16) {
        int c[16]; float w[16]; unsigned v[16];
#pragma unroll
        for (int u = 0; u < 16; ++u) { c[u] = scol[wave][j + u]; w[u] = sw[wave][j + u]; }
#pragma unroll
        for (int u = 0; u < 16; ++u) v[u] = xb[c[u] * 64 + lane];
#pragma unroll
        for (int u = 0; u < 16; ++u) { ax += w[u] * bf_lo(v[u]); ay += w[u] * bf_hi(v[u]); }
    }
    for (; j < d; ++j) {
        int cc = scol[wave][j];
        float w = sw[wave][j];
        unsigned v = xb[cc * 64 + lane];
        ax += w * bf_lo(v); ay += w * bf_hi(v);
    }
    float ox = ax * inv, oy = ay * inv;
    h0b[r * 64 + lane] = ((unsigned)bf16rne(oy) << 16) | (unsigned)bf16rne(ox);
}

// ---------------------------------------------------------------------------
// Gather SpMM (ELL, deduped weights in ed.y): one wave per row, 16 gathers in
// flight. fp32 accumulate. Epilogue: out = acc*invdeg + bias (fp32).
__global__ void spmm2_kernel(const unsigned* __restrict__ xb, const int* __restrict__ cur,
                             const int2* __restrict__ ed, const float* __restrict__ invdeg,
                             const float* __restrict__ bias, float* __restrict__ outp) {
    int wave = threadIdx.x >> 6, lane = threadIdx.x & 63;
    int r = blockIdx.x * 4 + wave;
    const int4* rowq = (const int4*)(ed + r * CAP);
    int d = cur[r];
    if (d > CAP) d = CAP;
    unsigned self = xb[r * 64 + lane];
    float ax = bf_lo(self), ay = bf_hi(self);
    int j = 0;
    for (; j + 16 <= d; j += 16) {
        int4 q[8]; int c[16]; float w[16]; unsigned v[16];
#pragma unroll
        for (int u = 0; u < 8; ++u) q[u] = rowq[(j >> 1) + u];
#pragma unroll
        for (int u = 0; u < 8; ++u) {
            c[2 * u] = q[u].x;     w[2 * u] = __int_as_float(q[u].y);
            c[2 * u + 1] = q[u].z; w[2 * u + 1] = __int_as_float(q[u].w);
        }
#pragma unroll
        for (int u = 0; u < 16; ++u) v[u] = xb[c[u] * 64 + lane];
#pragma unroll
        for (int u = 0; u < 16; ++u) { ax += w[u] * bf_lo(v[u]); ay += w[u] * bf_hi(v[u]); }
    }
    for (; j + 4 <= d; j += 4) {
        int4 q0 = rowq[j >> 1], q1 = rowq[(j >> 1) + 1];
        unsigned v0 = xb[q0.x * 64 + lane];
        unsigned v1 = xb[q0.z * 64 + lane];
        unsigned v2 = xb[q1.x * 64 + lane];
        unsigned v3 = xb[q1.z * 64 + lane];
        float w0 = __int_as_float(q0.y), w1 = __int_as_float(q0.w);
        float w2 = __int_as_float(q1.y), w3 = __int_as_float(q1.w);
        ax += w0 * bf_lo(v0) + w1 * bf_lo(v1) + w2 * bf_lo(v2) + w3 * bf_lo(v3);
        ay += w0 * bf_hi(v0) + w1 * bf_hi(v1) + w2 * bf_hi(v2) + w3 * bf_hi(v3);
    }
    const int2* row = (const int2*)(ed + r * CAP);
    for (; j < d; ++j) {
        int2 e = row[j];
        float w = __int_as_float(e.y);
        unsigned v = xb[e.x * 64 + lane];
        ax += w * bf_lo(v); ay += w * bf_hi(v);
    }
    float inv = invdeg[r];
    float ox = ax * inv + bias[2 * lane];
    float oy = ay * inv + bias[2 * lane + 1];
    ((float2*)outp)[r * 64 + lane] = make_float2(ox, oy);
}

// ---------------------------------------------------------------------------
// MFMA MLP: h2 = relu(LN(h0 @ W1 + b1)) @ W2  in bf16 (b2 added in spmm2).
// One wave owns 16 rows end-to-end; 4 waves/block (64 rows), grid 256.
// mfma_f32_16x16x32_bf16: C/D col=lane&15 row=quad*4+reg; A[m=lane&15][k=quad*8+j].
// W1t/W2t are [n][k] bf16 so B-frags are contiguous 16B loads (L1/L2-resident).
__launch_bounds__(256)
__global__ void mlp_mfma_kernel(const unsigned short* __restrict__ h0b,
                                const unsigned short* __restrict__ W1t,
                                const unsigned short* __restrict__ W2t,
                                const float* __restrict__ b1,
                                const float* __restrict__ ln_g, const float* __restrict__ ln_b,
                                unsigned short* __restrict__ h2b) {
    __shared__ unsigned short Hs[4][16 * HSTR];    // ~33 KB
    int t = threadIdx.x;
    int wid = t >> 6, lane = t & 63;
    int lnid = lane & 15, quad = lane >> 4;
    int R = blockIdx.x * 64 + wid * 16;
    unsigned short* H = Hs[wid];

    // ---- stage A: C1[16x256] = h0[R.., 128] @ W1, K=128 ----
    bf16x8 a[4];
#pragma unroll
    for (int ch = 0; ch < 4; ++ch)
        a[ch] = *(const bf16x8*)&h0b[(size_t)(R + lnid) * F_IN + ch * 32 + quad * 8];
    f32x4 acc[16];
#pragma unroll
    for (int ct = 0; ct < 16; ++ct) {
        f32x4 c = {0.0f, 0.0f, 0.0f, 0.0f};
        const unsigned short* wrow = &W1t[(size_t)(ct * 16 + lnid) * F_IN];
#pragma unroll
        for (int ch = 0; ch < 4; ++ch) {
            bf16x8 b = *(const bf16x8*)&wrow[ch * 32 + quad * 8];
            c = __builtin_amdgcn_mfma_f32_16x16x32_bf16(a[ch], b, c, 0, 0, 0);
        }
        acc[ct] = c;
    }
    // bias + LN stats (rows live in (quad,reg); cols in (ct,lnid))
    float s[4] = {0, 0, 0, 0}, q[4] = {0, 0, 0, 0};
#pragma unroll
    for (int ct = 0; ct < 16; ++ct) {
        float bv = b1[ct * 16 + lnid];
#pragma unroll
        for (int r = 0; r < 4; ++r) {
            float v = acc[ct][r] + bv;
            acc[ct][r] = v;
            s[r] += v; q[r] += v * v;
        }
    }
#pragma unroll
    for (int r = 0; r < 4; ++r)
        for (int off = 1; off < 16; off <<= 1) {
            s[r] += __shfl_xor(s[r], off, 64);
            q[r] += __shfl_xor(q[r], off, 64);
        }
    float mean[4], rinv[4];
#pragma unroll
    for (int r = 0; r < 4; ++r) {
        mean[r] = s[r] * (1.0f / F_HID);
        float var = q[r] * (1.0f / F_HID) - mean[r] * mean[r];
        rinv[r] = rsqrtf(var + LN_EPS);
    }
#pragma unroll
    for (int ct = 0; ct < 16; ++ct) {
        int c = ct * 16 + lnid;
        float g = ln_g[c], bb = ln_b[c];
#pragma unroll
        for (int r = 0; r < 4; ++r) {
            float v = fmaxf((acc[ct][r] - mean[r]) * rinv[r] * g + bb, 0.0f);
            H[(quad * 4 + r) * HSTR + c] = bf16rne(v);
        }
    }
    __syncthreads();   // drain LDS writes before A-layout reads

    // ---- stage B: C2[16x128] = H[16x256] @ W2, K=256 ----
    bf16x8 a2[8];
#pragma unroll
    for (int ch = 0; ch < 8; ++ch)
        a2[ch] = *(const bf16x8*)&H[lnid * HSTR + ch * 32 + quad * 8];
#pragma unroll
    for (int ct = 0; ct < 8; ++ct) {
        f32x4 c = {0.0f, 0.0f, 0.0f, 0.0f};
        const unsigned short* wrow = &W2t[(size_t)(ct * 16 + lnid) * F_HID];
#pragma unroll
        for (int ch = 0; ch < 8; ++ch) {
            bf16x8 b = *(const bf16x8*)&wrow[ch * 32 + quad * 8];
            c = __builtin_amdgcn_mfma_f32_16x16x32_bf16(a2[ch], b, c, 0, 0, 0);
        }
        // C2 -> LDS repack area (stride 132 ushorts)
#pragma unroll
        for (int r = 0; r < 4; ++r)
            H[(quad * 4 + r) * 132 + ct * 16 + lnid] = bf16rne(c[r]);
    }
    __syncthreads();   // drain before coalesced readback

    // coalesced store: 16 rows x 128 bf16
#pragma unroll
    for (int p = 0; p < 8; ++p) {
        int flat = p * 64 + lane;           // ushort4 id in [0,512)
        int m = flat >> 5, cg = flat & 31;
        *(ushort4*)&h2b[(size_t)(R + m) * F_OUT + cg * 4] =
            *(const ushort4*)&H[m * 132 + cg * 4];
    }
}

// ---------------------------------------------------------------------------
extern "C" void kernel_launch(void* const* d_in, const int* in_sizes, int n_in,
                              void* d_out, int out_size, void* d_ws, size_t ws_size,
                              hipStream_t stream) {
    const float* x   = (const float*)d_in[0];
    const void*  ei  = d_in[1];
    const float* ew  = (const float*)d_in[2];
    const float* W1  = (const float*)d_in[3];
    const float* b1  = (const float*)d_in[4];
    const float* W2  = (const float*)d_in[5];
    const float* b2  = (const float*)d_in[6];
    const float* lng = (const float*)d_in[7];
    const float* lnb = (const float*)d_in[8];
    float* out = (float*)d_out;
    int E = in_sizes[2];

    char* w = (char*)d_ws;
    size_t off = 0;
    auto take = [&](size_t bytes) -> char* {
        char* p = w + off;
        off += (bytes + 255) & ~(size_t)255;
        return p;
    };
    int*   cur    = (int*)take((size_t)N_NODES * 4);
    float* invdeg = (float*)take((size_t)N_NODES * 4);
    int2*  ed     = (int2*)take((size_t)N_NODES * CAP * 8);
    unsigned short* xb  = (unsigned short*)take((size_t)N_NODES * F_IN * 2);
    unsigned short* h0b = (unsigned short*)take((size_t)N_NODES * F_IN * 2);
    unsigned short* h2b = (unsigned short*)take((size_t)N_NODES * F_OUT * 2);
    unsigned short* W1t = (unsigned short*)take((size_t)F_IN * F_HID * 2);
    unsigned short* W2t = (unsigned short*)take((size_t)F_HID * F_OUT * 2);
    int*   mode   = (int*)take(4);

    prelude_kernel<<<2369, 256, 0, stream>>>(x, xb, W1, W1t, W2, W2t, cur,
                                             (const unsigned*)ei, mode);
    fill_kernel<<<(E + 1023) / 1024, 256, 0, stream>>>(ei, mode, cur, ed, E);
    // dedupe + h0b = bf16( D^-1 (A+I) x )
    dd_spmm1_kernel<<<N_NODES / 4, 256, 0, stream>>>(ew, cur, ed, invdeg,
                                                     (const unsigned*)xb, (unsigned*)h0b);
    // h2b = bf16( relu(LN(h0 W1 + b1)) W2 )
    mlp_mfma_kernel<<<N_NODES / 64, 256, 0, stream>>>(h0b, W1t, W2t, b1, lng, lnb, h2b);
    // out = D^-1 (A+I) h2 + b2   (== (D^-1 (A+I) h) W2 + b2 by linearity)
    spmm2_kernel<<<N_NODES / 4, 256, 0, stream>>>((const unsigned*)h2b, cur, ed, invdeg,
                                                  b2, out);
}